// Round 4
// baseline (323.590 us; speedup 1.0000x reference)
//
#include <hip/hip_runtime.h>

// Capsule dynamic routing, MI355X (gfx950).
// x (256,1152,8) f32, W (1152,8,10,16) f32, out v (256,10,16) f32.
// R3 -> R4: R3 was LDS-issue + latency bound (1.47M ds_read_b128/pass,
// conflicted staging writes, 20% occupancy). New structure:
//  - lane = (i_sub 8, oq 4, jg 2): j-range split across lanes -> u-cache
//    u[2][5][4] (40 regs) lives across phases => phase C re-reads NOTHING.
//    LDS reads and FMAs per pass both halve.
//  - identity W layout [i][d][j][o] is bank-conflict-free under this map
//    (quad = oq + 4*((jl^jg)&1)) => staging is a linear copy done with
//    global_load_lds dwordx4 (no ds_write at all), double-buffered
//    40KB+40KB with counted vmcnt + raw s_barrier.
//  - 2 rounds of 8 i's per block; round 1 accumulates into part via
//    same-thread RMW (keeps VGPR ~100 -> 2 blocks/CU).

#define NUM_IN 1152
#define NUM_OUT 10
#define OUT_DIM 16
#define BATCH 256
#define SLOTS 160
#define ICH_BLK 16
#define NCHUNK (NUM_IN / ICH_BLK)  // 72
#define BPB 16                     // batch elems per block (8 waves x 2)
#define NBT (BATCH / BPB)          // 16
#define WROW 1280                  // floats per i-row of W

typedef unsigned int __attribute__((address_space(1))) as1_uint;
typedef unsigned int __attribute__((address_space(3))) as3_uint;

__device__ __forceinline__ void gll16(const float* g, float* l) {
  __builtin_amdgcn_global_load_lds((const as1_uint*)g, (as3_uint*)l, 16, 0, 0);
}

// Sum over each aligned 8-lane group via DPP row_shr; valid at lanes with
// (lane&7)==7 (accumulation tree stays within the group for those lanes).
__device__ __forceinline__ float rowsum8_hi(float x) {
  int v;
  v = __builtin_amdgcn_update_dpp(0, __float_as_int(x), 0x114, 0xF, 0xF, true); // row_shr:4
  x += __int_as_float(v);
  v = __builtin_amdgcn_update_dpp(0, __float_as_int(x), 0x112, 0xF, 0xF, true); // row_shr:2
  x += __int_as_float(v);
  v = __builtin_amdgcn_update_dpp(0, __float_as_int(x), 0x111, 0xF, 0xF, true); // row_shr:1
  x += __int_as_float(v);
  return x;
}

// 16-lane full-row sum (all lanes get result) -- used by squash kernels.
__device__ __forceinline__ float rowsum16(float x) {
  int v;
  v = __builtin_amdgcn_update_dpp(0, __float_as_int(x), 0x128, 0xF, 0xF, true); // ror:8
  x += __int_as_float(v);
  v = __builtin_amdgcn_update_dpp(0, __float_as_int(x), 0x124, 0xF, 0xF, true); // ror:4
  x += __int_as_float(v);
  v = __builtin_amdgcn_update_dpp(0, __float_as_int(x), 0x122, 0xF, 0xF, true); // ror:2
  x += __int_as_float(v);
  v = __builtin_amdgcn_update_dpp(0, __float_as_int(x), 0x121, 0xF, 0xF, true); // ror:1
  x += __int_as_float(v);
  return x;
}

// One 8-i round. Wb = LDS buffer for this round. i = this thread's input
// capsule. Thread's j set: {jl + 5*jg, jl in 0..4}.
template <int PASS, int R, bool PART>
__device__ __forceinline__ void compute_round(
    const float* __restrict__ x, const float* __restrict__ v0p,
    const float* __restrict__ v1p, float* __restrict__ outp, const float* Wb,
    int i, int b0, int lbase, int vbase, size_t obase) {
  // x rows for the wave's two batch elements
  float xd[2][8];
#pragma unroll
  for (int bb = 0; bb < 2; ++bb) {
    const float* px = x + ((size_t)(b0 + bb) * NUM_IN + i) * 8;
    const float4 a = *reinterpret_cast<const float4*>(px);
    const float4 c = *reinterpret_cast<const float4*>(px + 4);
    xd[bb][0] = a.x; xd[bb][1] = a.y; xd[bb][2] = a.z; xd[bb][3] = a.w;
    xd[bb][4] = c.x; xd[bb][5] = c.y; xd[bb][6] = c.z; xd[bb][7] = c.w;
  }

  float u[2][5][4];   // cached u_hat fragments (o-quad) for this thread's 5 j's
  float cw[2][5];     // logits, then coupling coefficients

  // ---- phase A: u_hat + logits ----
#pragma unroll
  for (int jl = 0; jl < 5; ++jl) {
    float ax0 = 0.f, ay0 = 0.f, az0 = 0.f, aw0 = 0.f;
    float ax1 = 0.f, ay1 = 0.f, az1 = 0.f, aw1 = 0.f;
#pragma unroll
    for (int d = 0; d < 8; ++d) {
      const float4 w =
          *reinterpret_cast<const float4*>(Wb + lbase + d * 160 + jl * 16);
      ax0 = fmaf(xd[0][d], w.x, ax0); ay0 = fmaf(xd[0][d], w.y, ay0);
      az0 = fmaf(xd[0][d], w.z, az0); aw0 = fmaf(xd[0][d], w.w, aw0);
      ax1 = fmaf(xd[1][d], w.x, ax1); ay1 = fmaf(xd[1][d], w.y, ay1);
      az1 = fmaf(xd[1][d], w.z, az1); aw1 = fmaf(xd[1][d], w.w, aw1);
    }
    u[0][jl][0] = ax0; u[0][jl][1] = ay0; u[0][jl][2] = az0; u[0][jl][3] = aw0;
    u[1][jl][0] = ax1; u[1][jl][1] = ay1; u[1][jl][2] = az1; u[1][jl][3] = aw1;
    if (PASS >= 1) {
#pragma unroll
      for (int bb = 0; bb < 2; ++bb) {
        const float4 p = *reinterpret_cast<const float4*>(
            v0p + (b0 + bb) * SLOTS + vbase + jl * 16);
        float lgv = u[bb][jl][0] * p.x + u[bb][jl][1] * p.y +
                    u[bb][jl][2] * p.z + u[bb][jl][3] * p.w;
        if (PASS == 2) {
          const float4 q = *reinterpret_cast<const float4*>(
              v1p + (b0 + bb) * SLOTS + vbase + jl * 16);
          lgv += u[bb][jl][0] * q.x + u[bb][jl][1] * q.y +
                 u[bb][jl][2] * q.z + u[bb][jl][3] * q.w;
        }
        cw[bb][jl] = lgv;
      }
    }
  }

  // ---- coupling coefficients ----
  if (PASS == 0) {
#pragma unroll
    for (int bb = 0; bb < 2; ++bb)
#pragma unroll
      for (int jl = 0; jl < 5; ++jl) cw[bb][jl] = 0.1f;
  } else {
#pragma unroll
    for (int bb = 0; bb < 2; ++bb) {
      // finish o-reduction across the 4 oq lane groups (lane bits 3,4)
#pragma unroll
      for (int jl = 0; jl < 5; ++jl) {
        float v = cw[bb][jl];
        v += __shfl_xor(v, 8);
        v += __shfl_xor(v, 16);
        cw[bb][jl] = v;
      }
      // softmax over all 10 j (other 5 live in the jg-partner lane, bit 5)
      float m = cw[bb][0];
#pragma unroll
      for (int jl = 1; jl < 5; ++jl) m = fmaxf(m, cw[bb][jl]);
      m = fmaxf(m, __shfl_xor(m, 32));
      float z = 0.f;
#pragma unroll
      for (int jl = 0; jl < 5; ++jl) {
        cw[bb][jl] = __expf(cw[bb][jl] - m);
        z += cw[bb][jl];
      }
      z += __shfl_xor(z, 32);
      const float rz = 1.0f / z;
#pragma unroll
      for (int jl = 0; jl < 5; ++jl) cw[bb][jl] *= rz;
    }
  }

  // ---- phase C: weight cached u, reduce over 8 i_sub lanes, store ----
  const bool wr = ((threadIdx.x & 7) == 7);
#pragma unroll
  for (int jl = 0; jl < 5; ++jl) {
#pragma unroll
    for (int bb = 0; bb < 2; ++bb) {
      const float sx = rowsum8_hi(cw[bb][jl] * u[bb][jl][0]);
      const float sy = rowsum8_hi(cw[bb][jl] * u[bb][jl][1]);
      const float sz = rowsum8_hi(cw[bb][jl] * u[bb][jl][2]);
      const float sw = rowsum8_hi(cw[bb][jl] * u[bb][jl][3]);
      if (wr) {
        if (PART) {
          float4* q =
              reinterpret_cast<float4*>(outp + obase + bb * SLOTS + jl * 16);
          float4 f = {sx, sy, sz, sw};
          if (R == 1) {
            const float4 o = *q;
            f.x += o.x; f.y += o.y; f.z += o.z; f.w += o.w;
          }
          *q = f;
        } else {
          float* p = outp + obase + bb * SLOTS + jl * 16;
          atomicAdd(p + 0, sx); atomicAdd(p + 1, sy);
          atomicAdd(p + 2, sz); atomicAdd(p + 3, sw);
        }
      }
    }
  }
}

template <int PASS, bool PART>
__global__ __launch_bounds__(512, 4) void caps_pass(
    const float* __restrict__ x, const float* __restrict__ W,
    const float* __restrict__ v0, const float* __restrict__ v1,
    float* __restrict__ outp) {
  __shared__ float Ws[2][10240];  // 2 x 40KB, double-buffered rounds

  const int t = threadIdx.x;
  const int ic = blockIdx.x % NCHUNK;
  const int bt = blockIdx.x / NCHUNK;
  const int i0 = ic * ICH_BLK;

  // Stage both rounds linearly via global_load_lds (no ds_write, no VGPR).
  const float* wg = W + (size_t)i0 * WROW;
#pragma unroll
  for (int k = 0; k < 5; ++k)
    gll16(wg + (t + k * 512) * 4, &Ws[0][(t + k * 512) * 4]);
#pragma unroll
  for (int k = 0; k < 5; ++k)
    gll16(wg + 8 * WROW + (t + k * 512) * 4, &Ws[1][(t + k * 512) * 4]);

  const int lane = t & 63;
  const int wave = t >> 6;
  const int i_sub = lane & 7;        // DPP 8-group reduction axis
  const int oq = (lane >> 3) & 3;    // o-quad
  const int jg = lane >> 5;          // j-half: j = jl + 5*jg
  const int b0 = bt * BPB + wave * 2;
  // LDS float base: f4 index (i_sub*320 + oq + 20*jg); j/d offsets are imms.
  const int lbase = i_sub * 1280 + (oq + 20 * jg) * 4;
  const int vbase = jg * 80 + oq * 4;  // float offset within a 160-slot row
  const size_t obase =
      ((PART ? (size_t)ic * BATCH : (size_t)0) + b0) * SLOTS + vbase;

  asm volatile("s_waitcnt vmcnt(5)" ::: "memory");  // round-0 buffer ready
  __builtin_amdgcn_s_barrier();
  compute_round<PASS, 0, PART>(x, v0, v1, outp, &Ws[0][0], i0 + i_sub, b0,
                               lbase, vbase, obase);
  asm volatile("s_waitcnt vmcnt(0)" ::: "memory");  // round-1 buffer ready
  __builtin_amdgcn_s_barrier();
  compute_round<PASS, 1, PART>(x, v0, v1, outp, &Ws[1][0], i0 + 8 + i_sub, b0,
                               lbase, vbase, obase);
}

// v = squash(sum_ic part[ic][b][:]). One block per batch element.
__global__ __launch_bounds__(192) void caps_reduce_squash(
    const float* __restrict__ part, float* __restrict__ v_out) {
  const int b = blockIdx.x;
  const int t = threadIdx.x;
  if (t < SLOTS) {
    float sv = 0.0f;
#pragma unroll 8
    for (int ic = 0; ic < NCHUNK; ++ic)
      sv += part[((size_t)ic * BATCH + b) * SLOTS + t];
    const float sq = rowsum16(sv * sv);  // 16-lane rows == one j each
    const float scale = sq / (1.0f + sq) * rsqrtf(sq + 1e-8f);
    v_out[(size_t)b * SLOTS + t] = sv * scale;
  }
}

// Fallback squash for the atomic path (s_in/s_zero alias intentionally).
__global__ __launch_bounds__(192) void caps_squash(const float* s_in,
                                                   float* v_out,
                                                   float* s_zero) {
  const int b = blockIdx.x;
  const int t = threadIdx.x;
  if (t < SLOTS) {
    const float sv = s_in[(size_t)b * SLOTS + t];
    const float sq = rowsum16(sv * sv);
    const float scale = sq / (1.0f + sq) * rsqrtf(sq + 1e-8f);
    v_out[(size_t)b * SLOTS + t] = sv * scale;
    if (s_zero) s_zero[(size_t)b * SLOTS + t] = 0.0f;
  }
}

extern "C" void kernel_launch(void* const* d_in, const int* in_sizes, int n_in,
                              void* d_out, int out_size, void* d_ws,
                              size_t ws_size, hipStream_t stream) {
  const float* x = (const float*)d_in[0];  // (256,1152,8)
  const float* W = (const float*)d_in[1];  // (1152,8,10,16)
  float* out = (float*)d_out;              // (256,10,16)

  const size_t part_elems = (size_t)NCHUNK * BATCH * SLOTS;  // 2.95M
  const size_t need = (part_elems + 2 * BATCH * SLOTS) * sizeof(float);
  const dim3 pg(NCHUNK * NBT);  // 1152 blocks

  if (ws_size >= need) {
    float* part = (float*)d_ws;      // 11.25 MiB
    float* v0 = part + part_elems;   // 160 KB
    float* v1 = v0 + BATCH * SLOTS;  // 160 KB
    caps_pass<0, true><<<pg, 512, 0, stream>>>(x, W, nullptr, nullptr, part);
    caps_reduce_squash<<<BATCH, 192, 0, stream>>>(part, v0);
    caps_pass<1, true><<<pg, 512, 0, stream>>>(x, W, v0, nullptr, part);
    caps_reduce_squash<<<BATCH, 192, 0, stream>>>(part, v1);
    caps_pass<2, true><<<pg, 512, 0, stream>>>(x, W, v0, v1, part);
    caps_reduce_squash<<<BATCH, 192, 0, stream>>>(part, out);
  } else {
    // Atomic fallback (ws only needs s + v0 + v1).
    float* s_buf = (float*)d_ws;
    float* v0 = s_buf + BATCH * SLOTS;
    float* v1 = v0 + BATCH * SLOTS;
    hipMemsetAsync(s_buf, 0, (size_t)BATCH * SLOTS * sizeof(float), stream);
    caps_pass<0, false><<<pg, 512, 0, stream>>>(x, W, nullptr, nullptr, s_buf);
    caps_squash<<<BATCH, 192, 0, stream>>>(s_buf, v0, s_buf);
    caps_pass<1, false><<<pg, 512, 0, stream>>>(x, W, v0, nullptr, s_buf);
    caps_squash<<<BATCH, 192, 0, stream>>>(s_buf, v1, s_buf);
    caps_pass<2, false><<<pg, 512, 0, stream>>>(x, W, v0, v1, s_buf);
    caps_squash<<<BATCH, 192, 0, stream>>>(s_buf, out, nullptr);
  }
}

// Round 5
// 231.887 us; speedup vs baseline: 1.3955x; 1.3955x over previous
//
#include <hip/hip_runtime.h>

// Capsule dynamic routing, MI355X (gfx950).
// x (256,1152,8) f32, W (1152,8,10,16) f32, out v (256,10,16) f32.
// R4 -> R5: R4 regressed from two bugs.
//  (1) __launch_bounds__(512,4) is CUDA semantics = min BLOCKS/CU -> 32
//      waves/CU -> VGPR capped at 64 -> ~95-reg demand spilled (WRITE 364MB).
//      Now (512,2): 128 VGPR cap, no spills, still 2 blocks/CU.
//  (2) identity W layout had i-stride 1280 ≡ 0 mod 32 banks -> 8-way LDS
//      read conflicts (8.8M). Now LDS holds float4-chunks permuted as
//      [dj][oq][i_sub] realized by PER-LANE GLOBAL SOURCE addresses into
//      linear global_load_lds dests (decode is pure bit-ops). For fixed
//      (d,jl) a wave's 64 reads hit quad oq*8+i_sub: 32 quads x 2 lanes
//      = 2-way, which is free on wave64.

#define NUM_IN 1152
#define NUM_OUT 10
#define OUT_DIM 16
#define BATCH 256
#define SLOTS 160
#define ICH_BLK 16
#define NCHUNK (NUM_IN / ICH_BLK)  // 72
#define BPB 16                     // batch elems per block (8 waves x 2)
#define NBT (BATCH / BPB)          // 16
#define WROW 1280                  // floats per i-row of W

typedef unsigned int __attribute__((address_space(1))) as1_uint;
typedef unsigned int __attribute__((address_space(3))) as3_uint;

__device__ __forceinline__ void gll16(const float* g, float* l) {
  __builtin_amdgcn_global_load_lds((const as1_uint*)g, (as3_uint*)l, 16, 0, 0);
}

// Sum over each aligned 8-lane group via DPP row_shr; result valid at lanes
// with (lane&7)==7.
__device__ __forceinline__ float rowsum8_hi(float x) {
  int v;
  v = __builtin_amdgcn_update_dpp(0, __float_as_int(x), 0x114, 0xF, 0xF, true); // row_shr:4
  x += __int_as_float(v);
  v = __builtin_amdgcn_update_dpp(0, __float_as_int(x), 0x112, 0xF, 0xF, true); // row_shr:2
  x += __int_as_float(v);
  v = __builtin_amdgcn_update_dpp(0, __float_as_int(x), 0x111, 0xF, 0xF, true); // row_shr:1
  x += __int_as_float(v);
  return x;
}

// 16-lane full-row sum (all lanes get result) -- used by squash kernels.
__device__ __forceinline__ float rowsum16(float x) {
  int v;
  v = __builtin_amdgcn_update_dpp(0, __float_as_int(x), 0x128, 0xF, 0xF, true); // ror:8
  x += __int_as_float(v);
  v = __builtin_amdgcn_update_dpp(0, __float_as_int(x), 0x124, 0xF, 0xF, true); // ror:4
  x += __int_as_float(v);
  v = __builtin_amdgcn_update_dpp(0, __float_as_int(x), 0x122, 0xF, 0xF, true); // ror:2
  x += __int_as_float(v);
  v = __builtin_amdgcn_update_dpp(0, __float_as_int(x), 0x121, 0xF, 0xF, true); // ror:1
  x += __int_as_float(v);
  return x;
}

// One 8-i round. Wb = LDS buffer (chunk layout [dj][oq][i_sub]).
// Thread's j set: {jl + 5*jg, jl in 0..4}. lbase = jg*640 + oq*32 + i_sub*4.
template <int PASS, int R, bool PART>
__device__ __forceinline__ void compute_round(
    const float* __restrict__ x, const float* __restrict__ v0p,
    const float* __restrict__ v1p, float* __restrict__ outp, const float* Wb,
    int i, int b0, int lbase, int vbase, size_t obase) {
  // x rows for the wave's two batch elements
  float xd[2][8];
#pragma unroll
  for (int bb = 0; bb < 2; ++bb) {
    const float* px = x + ((size_t)(b0 + bb) * NUM_IN + i) * 8;
    const float4 a = *reinterpret_cast<const float4*>(px);
    const float4 c = *reinterpret_cast<const float4*>(px + 4);
    xd[bb][0] = a.x; xd[bb][1] = a.y; xd[bb][2] = a.z; xd[bb][3] = a.w;
    xd[bb][4] = c.x; xd[bb][5] = c.y; xd[bb][6] = c.z; xd[bb][7] = c.w;
  }

  float u[2][5][4];   // cached u_hat o-quad fragments for this thread's 5 j's
  float cw[2][5];     // logits, then coupling coefficients

  // ---- phase A: u_hat + logits ----
#pragma unroll
  for (int jl = 0; jl < 5; ++jl) {
    float ax0 = 0.f, ay0 = 0.f, az0 = 0.f, aw0 = 0.f;
    float ax1 = 0.f, ay1 = 0.f, az1 = 0.f, aw1 = 0.f;
#pragma unroll
    for (int d = 0; d < 8; ++d) {
      const float4 w =
          *reinterpret_cast<const float4*>(Wb + lbase + (d * 10 + jl) * 128);
      ax0 = fmaf(xd[0][d], w.x, ax0); ay0 = fmaf(xd[0][d], w.y, ay0);
      az0 = fmaf(xd[0][d], w.z, az0); aw0 = fmaf(xd[0][d], w.w, aw0);
      ax1 = fmaf(xd[1][d], w.x, ax1); ay1 = fmaf(xd[1][d], w.y, ay1);
      az1 = fmaf(xd[1][d], w.z, az1); aw1 = fmaf(xd[1][d], w.w, aw1);
    }
    u[0][jl][0] = ax0; u[0][jl][1] = ay0; u[0][jl][2] = az0; u[0][jl][3] = aw0;
    u[1][jl][0] = ax1; u[1][jl][1] = ay1; u[1][jl][2] = az1; u[1][jl][3] = aw1;
    if (PASS >= 1) {
#pragma unroll
      for (int bb = 0; bb < 2; ++bb) {
        const float4 p = *reinterpret_cast<const float4*>(
            v0p + (b0 + bb) * SLOTS + vbase + jl * 16);
        float lgv = u[bb][jl][0] * p.x + u[bb][jl][1] * p.y +
                    u[bb][jl][2] * p.z + u[bb][jl][3] * p.w;
        if (PASS == 2) {
          const float4 q = *reinterpret_cast<const float4*>(
              v1p + (b0 + bb) * SLOTS + vbase + jl * 16);
          lgv += u[bb][jl][0] * q.x + u[bb][jl][1] * q.y +
                 u[bb][jl][2] * q.z + u[bb][jl][3] * q.w;
        }
        cw[bb][jl] = lgv;
      }
    }
  }

  // ---- coupling coefficients ----
  if (PASS == 0) {
#pragma unroll
    for (int bb = 0; bb < 2; ++bb)
#pragma unroll
      for (int jl = 0; jl < 5; ++jl) cw[bb][jl] = 0.1f;
  } else {
#pragma unroll
    for (int bb = 0; bb < 2; ++bb) {
      // finish o-reduction across the 4 oq lane groups (lane bits 3,4)
#pragma unroll
      for (int jl = 0; jl < 5; ++jl) {
        float v = cw[bb][jl];
        v += __shfl_xor(v, 8);
        v += __shfl_xor(v, 16);
        cw[bb][jl] = v;
      }
      // softmax over all 10 j (other 5 live in the jg-partner lane, bit 5)
      float m = cw[bb][0];
#pragma unroll
      for (int jl = 1; jl < 5; ++jl) m = fmaxf(m, cw[bb][jl]);
      m = fmaxf(m, __shfl_xor(m, 32));
      float z = 0.f;
#pragma unroll
      for (int jl = 0; jl < 5; ++jl) {
        cw[bb][jl] = __expf(cw[bb][jl] - m);
        z += cw[bb][jl];
      }
      z += __shfl_xor(z, 32);
      const float rz = 1.0f / z;
#pragma unroll
      for (int jl = 0; jl < 5; ++jl) cw[bb][jl] *= rz;
    }
  }

  // ---- phase C: weight cached u, reduce over 8 i_sub lanes, store ----
  const bool wr = ((threadIdx.x & 7) == 7);
#pragma unroll
  for (int jl = 0; jl < 5; ++jl) {
#pragma unroll
    for (int bb = 0; bb < 2; ++bb) {
      const float sx = rowsum8_hi(cw[bb][jl] * u[bb][jl][0]);
      const float sy = rowsum8_hi(cw[bb][jl] * u[bb][jl][1]);
      const float sz = rowsum8_hi(cw[bb][jl] * u[bb][jl][2]);
      const float sw = rowsum8_hi(cw[bb][jl] * u[bb][jl][3]);
      if (wr) {
        if (PART) {
          float4* q =
              reinterpret_cast<float4*>(outp + obase + bb * SLOTS + jl * 16);
          float4 f = {sx, sy, sz, sw};
          if (R == 1) {
            const float4 o = *q;
            f.x += o.x; f.y += o.y; f.z += o.z; f.w += o.w;
          }
          *q = f;
        } else {
          float* p = outp + obase + bb * SLOTS + jl * 16;
          atomicAdd(p + 0, sx); atomicAdd(p + 1, sy);
          atomicAdd(p + 2, sz); atomicAdd(p + 3, sw);
        }
      }
    }
  }
}

template <int PASS, bool PART>
__global__ __launch_bounds__(512, 2) void caps_pass(
    const float* __restrict__ x, const float* __restrict__ W,
    const float* __restrict__ v0, const float* __restrict__ v1,
    float* __restrict__ outp) {
  __shared__ float Ws[2][10240];  // 2 x 40KB, double-buffered rounds

  const int t = threadIdx.x;
  const int ic = blockIdx.x % NCHUNK;
  const int bt = blockIdx.x / NCHUNK;
  const int i0 = ic * ICH_BLK;

  // Stage both rounds. LDS chunk p (16B granules) holds global chunk
  // g = i*320 + dj*4 + oq where i=p&7, oq=(p>>3)&3, dj=p>>5 (pure bit-ops;
  // per-lane global source, linear LDS dest).
  const float* wg = W + (size_t)i0 * WROW;
#pragma unroll
  for (int k = 0; k < 5; ++k) {
    const int p = t + k * 512;
    const int g = (p & 7) * 320 + (p >> 5) * 4 + ((p >> 3) & 3);
    gll16(wg + g * 4, &Ws[0][p * 4]);
  }
#pragma unroll
  for (int k = 0; k < 5; ++k) {
    const int p = t + k * 512;
    const int g = (p & 7) * 320 + (p >> 5) * 4 + ((p >> 3) & 3);
    gll16(wg + 8 * WROW + g * 4, &Ws[1][p * 4]);
  }

  const int lane = t & 63;
  const int wave = t >> 6;
  const int i_sub = lane & 7;        // DPP 8-group reduction axis
  const int oq = (lane >> 3) & 3;    // o-quad
  const int jg = lane >> 5;          // j-half: j = jl + 5*jg
  const int b0 = bt * BPB + wave * 2;
  const int lbase = jg * 640 + oq * 32 + i_sub * 4;  // float idx of chunk base
  const int vbase = jg * 80 + oq * 4;  // float offset within a 160-slot row
  const size_t obase =
      ((PART ? (size_t)ic * BATCH : (size_t)0) + b0) * SLOTS + vbase;

  asm volatile("s_waitcnt vmcnt(5)" ::: "memory");  // round-0 buffer ready
  __builtin_amdgcn_s_barrier();
  compute_round<PASS, 0, PART>(x, v0, v1, outp, &Ws[0][0], i0 + i_sub, b0,
                               lbase, vbase, obase);
  asm volatile("s_waitcnt vmcnt(0)" ::: "memory");  // round-1 buffer ready
  __builtin_amdgcn_s_barrier();
  compute_round<PASS, 1, PART>(x, v0, v1, outp, &Ws[1][0], i0 + 8 + i_sub, b0,
                               lbase, vbase, obase);
}

// v = squash(sum_ic part[ic][b][:]). One block per batch element.
__global__ __launch_bounds__(192) void caps_reduce_squash(
    const float* __restrict__ part, float* __restrict__ v_out) {
  const int b = blockIdx.x;
  const int t = threadIdx.x;
  if (t < SLOTS) {
    float sv = 0.0f;
#pragma unroll 8
    for (int ic = 0; ic < NCHUNK; ++ic)
      sv += part[((size_t)ic * BATCH + b) * SLOTS + t];
    const float sq = rowsum16(sv * sv);  // 16-lane rows == one j each
    const float scale = sq / (1.0f + sq) * rsqrtf(sq + 1e-8f);
    v_out[(size_t)b * SLOTS + t] = sv * scale;
  }
}

// Fallback squash for the atomic path (s_in/s_zero alias intentionally).
__global__ __launch_bounds__(192) void caps_squash(const float* s_in,
                                                   float* v_out,
                                                   float* s_zero) {
  const int b = blockIdx.x;
  const int t = threadIdx.x;
  if (t < SLOTS) {
    const float sv = s_in[(size_t)b * SLOTS + t];
    const float sq = rowsum16(sv * sv);
    const float scale = sq / (1.0f + sq) * rsqrtf(sq + 1e-8f);
    v_out[(size_t)b * SLOTS + t] = sv * scale;
    if (s_zero) s_zero[(size_t)b * SLOTS + t] = 0.0f;
  }
}

extern "C" void kernel_launch(void* const* d_in, const int* in_sizes, int n_in,
                              void* d_out, int out_size, void* d_ws,
                              size_t ws_size, hipStream_t stream) {
  const float* x = (const float*)d_in[0];  // (256,1152,8)
  const float* W = (const float*)d_in[1];  // (1152,8,10,16)
  float* out = (float*)d_out;              // (256,10,16)

  const size_t part_elems = (size_t)NCHUNK * BATCH * SLOTS;  // 2.95M
  const size_t need = (part_elems + 2 * BATCH * SLOTS) * sizeof(float);
  const dim3 pg(NCHUNK * NBT);  // 1152 blocks

  if (ws_size >= need) {
    float* part = (float*)d_ws;      // 11.25 MiB
    float* v0 = part + part_elems;   // 160 KB
    float* v1 = v0 + BATCH * SLOTS;  // 160 KB
    caps_pass<0, true><<<pg, 512, 0, stream>>>(x, W, nullptr, nullptr, part);
    caps_reduce_squash<<<BATCH, 192, 0, stream>>>(part, v0);
    caps_pass<1, true><<<pg, 512, 0, stream>>>(x, W, v0, nullptr, part);
    caps_reduce_squash<<<BATCH, 192, 0, stream>>>(part, v1);
    caps_pass<2, true><<<pg, 512, 0, stream>>>(x, W, v0, v1, part);
    caps_reduce_squash<<<BATCH, 192, 0, stream>>>(part, out);
  } else {
    // Atomic fallback (ws only needs s + v0 + v1).
    float* s_buf = (float*)d_ws;
    float* v0 = s_buf + BATCH * SLOTS;
    float* v1 = v0 + BATCH * SLOTS;
    hipMemsetAsync(s_buf, 0, (size_t)BATCH * SLOTS * sizeof(float), stream);
    caps_pass<0, false><<<pg, 512, 0, stream>>>(x, W, nullptr, nullptr, s_buf);
    caps_squash<<<BATCH, 192, 0, stream>>>(s_buf, v0, s_buf);
    caps_pass<1, false><<<pg, 512, 0, stream>>>(x, W, v0, nullptr, s_buf);
    caps_squash<<<BATCH, 192, 0, stream>>>(s_buf, v1, s_buf);
    caps_pass<2, false><<<pg, 512, 0, stream>>>(x, W, v0, v1, s_buf);
    caps_squash<<<BATCH, 192, 0, stream>>>(s_buf, out, nullptr);
  }
}

// Round 6
// 229.510 us; speedup vs baseline: 1.4099x; 1.0104x over previous
//
#include <hip/hip_runtime.h>

// Capsule dynamic routing, MI355X (gfx950).
// x (256,1152,8) f32, W (1152,8,10,16) f32, out v (256,10,16) f32.
// R5 -> R6: R5 was latency-exposure bound (VALUBusy 30%, occ 18%,
// pipe-floor ~15us vs 61us measured). Changes:
//  (1) lane map (i_sub b0-2, oq_lo b3, jg b4, oq_hi b5): o-reduction is now
//      row_ror:8 (DPP) + permlane32_swap (VALU) -- off the LDS pipe.
//  (2) x loads hoisted above the W-stage waits (order pinned by
//      sched_barrier(0); buf0+x ... buf1 ... vmcnt(5)) so x latency hides
//      under W staging.
//  (3) part transposed to [b][ic][slot]: squash reads coalesce at 640B
//      stride instead of 160KB stride.

#define NUM_IN 1152
#define NUM_OUT 10
#define OUT_DIM 16
#define BATCH 256
#define SLOTS 160
#define ICH_BLK 16
#define NCHUNK (NUM_IN / ICH_BLK)  // 72
#define BPB 16                     // batch elems per block (8 waves x 2)
#define NBT (BATCH / BPB)          // 16
#define WROW 1280                  // floats per i-row of W

typedef unsigned int __attribute__((address_space(1))) as1_uint;
typedef unsigned int __attribute__((address_space(3))) as3_uint;
typedef int v2i __attribute__((ext_vector_type(2)));

__device__ __forceinline__ void gll16(const float* g, float* l) {
  __builtin_amdgcn_global_load_lds((const as1_uint*)g, (as3_uint*)l, 16, 0, 0);
}

// x + x^8 within each 16-lane row (row_ror:8 is xor-8 in a 16-ring).
__device__ __forceinline__ float xor8_sum(float x) {
  int v = __builtin_amdgcn_update_dpp(0, __float_as_int(x), 0x128, 0xF, 0xF, true);
  return x + __int_as_float(v);
}

// x[l&31] + x[l|32] in every lane via permlane32_swap (VALU, no LDS pipe).
// With both operands = x, the two results are {x.lo,x.lo} and {x.hi,x.hi}
// (in some order) -> their sum is the xor-32 pair sum in all lanes.
__device__ __forceinline__ float xor32_sum(float x) {
  v2i r = __builtin_amdgcn_permlane32_swap(__float_as_int(x),
                                           __float_as_int(x), false, false);
  return __int_as_float(r.x) + __int_as_float(r.y);
}

// Sum over each aligned 8-lane group via DPP row_shr; result valid at lanes
// with (lane&7)==7.
__device__ __forceinline__ float rowsum8_hi(float x) {
  int v;
  v = __builtin_amdgcn_update_dpp(0, __float_as_int(x), 0x114, 0xF, 0xF, true); // row_shr:4
  x += __int_as_float(v);
  v = __builtin_amdgcn_update_dpp(0, __float_as_int(x), 0x112, 0xF, 0xF, true); // row_shr:2
  x += __int_as_float(v);
  v = __builtin_amdgcn_update_dpp(0, __float_as_int(x), 0x111, 0xF, 0xF, true); // row_shr:1
  x += __int_as_float(v);
  return x;
}

// 16-lane full-row sum (all lanes get result) -- used by squash kernels.
__device__ __forceinline__ float rowsum16(float x) {
  int v;
  v = __builtin_amdgcn_update_dpp(0, __float_as_int(x), 0x128, 0xF, 0xF, true); // ror:8
  x += __int_as_float(v);
  v = __builtin_amdgcn_update_dpp(0, __float_as_int(x), 0x124, 0xF, 0xF, true); // ror:4
  x += __int_as_float(v);
  v = __builtin_amdgcn_update_dpp(0, __float_as_int(x), 0x122, 0xF, 0xF, true); // ror:2
  x += __int_as_float(v);
  v = __builtin_amdgcn_update_dpp(0, __float_as_int(x), 0x121, 0xF, 0xF, true); // ror:1
  x += __int_as_float(v);
  return x;
}

// One 8-i round. Wb: LDS chunk layout [d][jl][lane]; lane encodes
// (i_sub, oq_lo, jg, oq_hi). xv: this round's hoisted x float4s [bb][half].
template <int PASS, int R, bool PART>
__device__ __forceinline__ void compute_round(
    const float4 xv[2][2], const float* __restrict__ v0p,
    const float* __restrict__ v1p, float* __restrict__ outp, const float* Wb,
    int b0, int lane, int vbase, size_t obase) {
  constexpr size_t BBS = PART ? (size_t)(NCHUNK * SLOTS) : (size_t)SLOTS;
  const float* wsl = Wb + lane * 4;

  float xd[2][8];
#pragma unroll
  for (int bb = 0; bb < 2; ++bb) {
    xd[bb][0] = xv[bb][0].x; xd[bb][1] = xv[bb][0].y;
    xd[bb][2] = xv[bb][0].z; xd[bb][3] = xv[bb][0].w;
    xd[bb][4] = xv[bb][1].x; xd[bb][5] = xv[bb][1].y;
    xd[bb][6] = xv[bb][1].z; xd[bb][7] = xv[bb][1].w;
  }

  float u[2][5][4];   // cached u_hat o-quad fragments for this thread's 5 j's
  float cw[2][5];     // logits, then coupling coefficients

  // ---- phase A: u_hat + logits ----
#pragma unroll
  for (int jl = 0; jl < 5; ++jl) {
    float ax0 = 0.f, ay0 = 0.f, az0 = 0.f, aw0 = 0.f;
    float ax1 = 0.f, ay1 = 0.f, az1 = 0.f, aw1 = 0.f;
#pragma unroll
    for (int d = 0; d < 8; ++d) {
      const float4 w =
          *reinterpret_cast<const float4*>(wsl + (d * 5 + jl) * 256);
      ax0 = fmaf(xd[0][d], w.x, ax0); ay0 = fmaf(xd[0][d], w.y, ay0);
      az0 = fmaf(xd[0][d], w.z, az0); aw0 = fmaf(xd[0][d], w.w, aw0);
      ax1 = fmaf(xd[1][d], w.x, ax1); ay1 = fmaf(xd[1][d], w.y, ay1);
      az1 = fmaf(xd[1][d], w.z, az1); aw1 = fmaf(xd[1][d], w.w, aw1);
    }
    u[0][jl][0] = ax0; u[0][jl][1] = ay0; u[0][jl][2] = az0; u[0][jl][3] = aw0;
    u[1][jl][0] = ax1; u[1][jl][1] = ay1; u[1][jl][2] = az1; u[1][jl][3] = aw1;
    if (PASS >= 1) {
#pragma unroll
      for (int bb = 0; bb < 2; ++bb) {
        const float4 p = *reinterpret_cast<const float4*>(
            v0p + (b0 + bb) * SLOTS + vbase + jl * 16);
        float lgv = u[bb][jl][0] * p.x + u[bb][jl][1] * p.y +
                    u[bb][jl][2] * p.z + u[bb][jl][3] * p.w;
        if (PASS == 2) {
          const float4 q = *reinterpret_cast<const float4*>(
              v1p + (b0 + bb) * SLOTS + vbase + jl * 16);
          lgv += u[bb][jl][0] * q.x + u[bb][jl][1] * q.y +
                 u[bb][jl][2] * q.z + u[bb][jl][3] * q.w;
        }
        // o-reduction over oq bits (lane bits 3 and 5): all-VALU.
        cw[bb][jl] = xor32_sum(xor8_sum(lgv));
      }
    }
  }

  // ---- coupling coefficients ----
  if (PASS == 0) {
#pragma unroll
    for (int bb = 0; bb < 2; ++bb)
#pragma unroll
      for (int jl = 0; jl < 5; ++jl) cw[bb][jl] = 0.1f;
  } else {
#pragma unroll
    for (int bb = 0; bb < 2; ++bb) {
      // softmax over all 10 j (other 5 j's live in the jg-partner, bit 4)
      float m = cw[bb][0];
#pragma unroll
      for (int jl = 1; jl < 5; ++jl) m = fmaxf(m, cw[bb][jl]);
      m = fmaxf(m, __shfl_xor(m, 16));
      float z = 0.f;
#pragma unroll
      for (int jl = 0; jl < 5; ++jl) {
        cw[bb][jl] = __expf(cw[bb][jl] - m);
        z += cw[bb][jl];
      }
      z += __shfl_xor(z, 16);
      const float rz = 1.0f / z;
#pragma unroll
      for (int jl = 0; jl < 5; ++jl) cw[bb][jl] *= rz;
    }
  }

  // ---- phase C: weight cached u, reduce over 8 i_sub lanes, store ----
  const bool wr = ((lane & 7) == 7);
#pragma unroll
  for (int jl = 0; jl < 5; ++jl) {
#pragma unroll
    for (int bb = 0; bb < 2; ++bb) {
      const float sx = rowsum8_hi(cw[bb][jl] * u[bb][jl][0]);
      const float sy = rowsum8_hi(cw[bb][jl] * u[bb][jl][1]);
      const float sz = rowsum8_hi(cw[bb][jl] * u[bb][jl][2]);
      const float sw = rowsum8_hi(cw[bb][jl] * u[bb][jl][3]);
      if (wr) {
        if (PART) {
          float4* q =
              reinterpret_cast<float4*>(outp + obase + bb * BBS + jl * 16);
          float4 f = {sx, sy, sz, sw};
          if (R == 1) {
            const float4 o = *q;
            f.x += o.x; f.y += o.y; f.z += o.z; f.w += o.w;
          }
          *q = f;
        } else {
          float* p = outp + obase + bb * BBS + jl * 16;
          atomicAdd(p + 0, sx); atomicAdd(p + 1, sy);
          atomicAdd(p + 2, sz); atomicAdd(p + 3, sw);
        }
      }
    }
  }
}

template <int PASS, bool PART>
__global__ __launch_bounds__(512, 2) void caps_pass(
    const float* __restrict__ x, const float* __restrict__ W,
    const float* __restrict__ v0, const float* __restrict__ v1,
    float* __restrict__ outp) {
  __shared__ float Ws[2][10240];  // 2 x 40KB, double-buffered rounds

  const int t = threadIdx.x;
  const int ic = blockIdx.x % NCHUNK;
  const int bt = blockIdx.x / NCHUNK;
  const int i0 = ic * ICH_BLK;

  const int lane = t & 63;
  const int wave = t >> 6;
  const int i_sub = lane & 7;                         // DPP 8-group axis
  const int oq = ((lane >> 3) & 1) | ((lane >> 4) & 2);  // bits 3,5
  const int jg = (lane >> 4) & 1;                     // bit 4
  const int b0 = bt * BPB + wave * 2;
  const int vbase = jg * 80 + oq * 4;

  // ---- issue round-0 staging ----
  // LDS chunk p holds W[i0 + (p&63 -> i_sub), d, jl+5*jg, oq] with
  // d=(p>>6)/5, jl=(p>>6)%5 and (i_sub,oq_lo,jg,oq_hi) from lane bits of p.
  const float* wg = W + (size_t)i0 * WROW;
#pragma unroll
  for (int k = 0; k < 5; ++k) {
    const int p = t + k * 512;
    const int lp = p & 63;
    const int dj = p >> 6;
    const int d = dj / 5, jl = dj % 5;
    const int g = (lp & 7) * 320 + d * 40 + jl * 4 + ((lp >> 4) & 1) * 20 +
                  ((lp >> 3) & 1) + ((lp >> 5) & 1) * 2;
    gll16(wg + g * 4, &Ws[0][p * 4]);
  }

  // ---- hoisted x loads (overlap W staging latency) ----
  float4 xv[2][2][2];  // [round][bb][half]
#pragma unroll
  for (int r = 0; r < 2; ++r)
#pragma unroll
    for (int bb = 0; bb < 2; ++bb) {
      const float* px =
          x + ((size_t)(b0 + bb) * NUM_IN + i0 + r * 8 + i_sub) * 8;
      xv[r][bb][0] = *reinterpret_cast<const float4*>(px);
      xv[r][bb][1] = *reinterpret_cast<const float4*>(px + 4);
    }

  __builtin_amdgcn_sched_barrier(0);  // pin: buf1 staging issues after x

  // ---- issue round-1 staging ----
#pragma unroll
  for (int k = 0; k < 5; ++k) {
    const int p = t + k * 512;
    const int lp = p & 63;
    const int dj = p >> 6;
    const int d = dj / 5, jl = dj % 5;
    const int g = (lp & 7) * 320 + d * 40 + jl * 4 + ((lp >> 4) & 1) * 20 +
                  ((lp >> 3) & 1) + ((lp >> 5) & 1) * 2;
    gll16(wg + 8 * WROW + g * 4, &Ws[1][p * 4]);
  }
  __builtin_amdgcn_sched_barrier(0);  // pin: vmcnt counts from here

  const size_t obase =
      PART ? ((size_t)b0 * NCHUNK + ic) * SLOTS + vbase
           : (size_t)b0 * SLOTS + vbase;

  // buf0 + x done (only buf1's 5 loads may remain outstanding)
  asm volatile("s_waitcnt vmcnt(5)" ::: "memory");
  __builtin_amdgcn_s_barrier();
  compute_round<PASS, 0, PART>(xv[0], v0, v1, outp, &Ws[0][0], b0, lane,
                               vbase, obase);
  asm volatile("s_waitcnt vmcnt(0)" ::: "memory");  // buf1 ready
  __builtin_amdgcn_s_barrier();
  compute_round<PASS, 1, PART>(xv[1], v0, v1, outp, &Ws[1][0], b0, lane,
                               vbase, obase);
}

// v = squash(sum_ic part[b][ic][:]). One block per batch element.
// part layout [b][ic][slot] -> reads stride 640B, coalesced across t.
__global__ __launch_bounds__(192) void caps_reduce_squash(
    const float* __restrict__ part, float* __restrict__ v_out) {
  const int b = blockIdx.x;
  const int t = threadIdx.x;
  if (t < SLOTS) {
    const float* pb = part + (size_t)b * NCHUNK * SLOTS + t;
    float sv = 0.0f;
#pragma unroll 8
    for (int ic = 0; ic < NCHUNK; ++ic) sv += pb[ic * SLOTS];
    const float sq = rowsum16(sv * sv);  // 16-lane rows == one j each
    const float scale = sq / (1.0f + sq) * rsqrtf(sq + 1e-8f);
    v_out[(size_t)b * SLOTS + t] = sv * scale;
  }
}

// Fallback squash for the atomic path (s_in/s_zero alias intentionally).
__global__ __launch_bounds__(192) void caps_squash(const float* s_in,
                                                   float* v_out,
                                                   float* s_zero) {
  const int b = blockIdx.x;
  const int t = threadIdx.x;
  if (t < SLOTS) {
    const float sv = s_in[(size_t)b * SLOTS + t];
    const float sq = rowsum16(sv * sv);
    const float scale = sq / (1.0f + sq) * rsqrtf(sq + 1e-8f);
    v_out[(size_t)b * SLOTS + t] = sv * scale;
    if (s_zero) s_zero[(size_t)b * SLOTS + t] = 0.0f;
  }
}

extern "C" void kernel_launch(void* const* d_in, const int* in_sizes, int n_in,
                              void* d_out, int out_size, void* d_ws,
                              size_t ws_size, hipStream_t stream) {
  const float* x = (const float*)d_in[0];  // (256,1152,8)
  const float* W = (const float*)d_in[1];  // (1152,8,10,16)
  float* out = (float*)d_out;              // (256,10,16)

  const size_t part_elems = (size_t)NCHUNK * BATCH * SLOTS;  // 2.95M
  const size_t need = (part_elems + 2 * BATCH * SLOTS) * sizeof(float);
  const dim3 pg(NCHUNK * NBT);  // 1152 blocks

  if (ws_size >= need) {
    float* part = (float*)d_ws;      // 11.25 MiB, layout [b][ic][slot]
    float* v0 = part + part_elems;   // 160 KB
    float* v1 = v0 + BATCH * SLOTS;  // 160 KB
    caps_pass<0, true><<<pg, 512, 0, stream>>>(x, W, nullptr, nullptr, part);
    caps_reduce_squash<<<BATCH, 192, 0, stream>>>(part, v0);
    caps_pass<1, true><<<pg, 512, 0, stream>>>(x, W, v0, nullptr, part);
    caps_reduce_squash<<<BATCH, 192, 0, stream>>>(part, v1);
    caps_pass<2, true><<<pg, 512, 0, stream>>>(x, W, v0, v1, part);
    caps_reduce_squash<<<BATCH, 192, 0, stream>>>(part, out);
  } else {
    // Atomic fallback (ws only needs s + v0 + v1).
    float* s_buf = (float*)d_ws;
    float* v0 = s_buf + BATCH * SLOTS;
    float* v1 = v0 + BATCH * SLOTS;
    hipMemsetAsync(s_buf, 0, (size_t)BATCH * SLOTS * sizeof(float), stream);
    caps_pass<0, false><<<pg, 512, 0, stream>>>(x, W, nullptr, nullptr, s_buf);
    caps_squash<<<BATCH, 192, 0, stream>>>(s_buf, v0, s_buf);
    caps_pass<1, false><<<pg, 512, 0, stream>>>(x, W, v0, nullptr, s_buf);
    caps_squash<<<BATCH, 192, 0, stream>>>(s_buf, v1, s_buf);
    caps_pass<2, false><<<pg, 512, 0, stream>>>(x, W, v0, v1, s_buf);
    caps_squash<<<BATCH, 192, 0, stream>>>(s_buf, out, nullptr);
  }
}

// Round 8
// 197.180 us; speedup vs baseline: 1.6411x; 1.1640x over previous
//
#include <hip/hip_runtime.h>

// Capsule dynamic routing, MI355X (gfx950).
// x (256,1152,8) f32, W (1152,8,10,16) f32, out v (256,10,16) f32.
// R7 -> R8: R7 was a pure compile failure (cvt_pkrtz returns __fp16x2,
// not _Float16x2). Typedef fixed; theory unchanged from R7:
//  - single 40KB LDS buffer (stage/compute/barrier/stage/compute); 4
//    blocks/CU overlap the re-stage bubbles.
//  - u-cache and x rows packed to f16 (cvt_pkrtz): live set ~60 VGPR.
//    Logits still use f32 u; only the s-sum sees f16 rounding (~1e-4 in v,
//    threshold 3.8e-3).
//  - __launch_bounds__(512,4): on this compiler arg2 == blocks/CU (R4/R5
//    counter evidence) -> VGPR capped at 64, now sized to fit.
//  - keep R6's VALU o-reduce (DPP ror:8 + permlane32_swap) and the part
//    [b][ic][slot] transpose; no sched_barrier pins; x loads inside round.

#define NUM_IN 1152
#define NUM_OUT 10
#define OUT_DIM 16
#define BATCH 256
#define SLOTS 160
#define ICH_BLK 16
#define NCHUNK (NUM_IN / ICH_BLK)  // 72
#define BPB 16                     // batch elems per block (8 waves x 2)
#define NBT (BATCH / BPB)          // 16
#define WROW 1280                  // floats per i-row of W

typedef unsigned int __attribute__((address_space(1))) as1_uint;
typedef unsigned int __attribute__((address_space(3))) as3_uint;
typedef int v2i __attribute__((ext_vector_type(2)));
typedef __fp16 h2 __attribute__((ext_vector_type(2)));

__device__ __forceinline__ void gll16(const float* g, float* l) {
  __builtin_amdgcn_global_load_lds((const as1_uint*)g, (as3_uint*)l, 16, 0, 0);
}

// x + x^8 within each 16-lane row (row_ror:8 == xor-8 in a 16-ring).
__device__ __forceinline__ float xor8_sum(float x) {
  int v = __builtin_amdgcn_update_dpp(0, __float_as_int(x), 0x128, 0xF, 0xF, true);
  return x + __int_as_float(v);
}

// Pair-sum across the lane<32 / lane>=32 halves via permlane32_swap (VALU
// pipe, no LDS). Proven in R6.
__device__ __forceinline__ float xor32_sum(float x) {
  v2i r = __builtin_amdgcn_permlane32_swap(__float_as_int(x),
                                           __float_as_int(x), false, false);
  return __int_as_float(r.x) + __int_as_float(r.y);
}

// Sum over each aligned 8-lane group via DPP row_shr; result valid at lanes
// with (lane&7)==7.
__device__ __forceinline__ float rowsum8_hi(float x) {
  int v;
  v = __builtin_amdgcn_update_dpp(0, __float_as_int(x), 0x114, 0xF, 0xF, true); // row_shr:4
  x += __int_as_float(v);
  v = __builtin_amdgcn_update_dpp(0, __float_as_int(x), 0x112, 0xF, 0xF, true); // row_shr:2
  x += __int_as_float(v);
  v = __builtin_amdgcn_update_dpp(0, __float_as_int(x), 0x111, 0xF, 0xF, true); // row_shr:1
  x += __int_as_float(v);
  return x;
}

// 16-lane full-row sum (all lanes get result) -- squash kernels.
__device__ __forceinline__ float rowsum16(float x) {
  int v;
  v = __builtin_amdgcn_update_dpp(0, __float_as_int(x), 0x128, 0xF, 0xF, true); // ror:8
  x += __int_as_float(v);
  v = __builtin_amdgcn_update_dpp(0, __float_as_int(x), 0x124, 0xF, 0xF, true); // ror:4
  x += __int_as_float(v);
  v = __builtin_amdgcn_update_dpp(0, __float_as_int(x), 0x122, 0xF, 0xF, true); // ror:2
  x += __int_as_float(v);
  v = __builtin_amdgcn_update_dpp(0, __float_as_int(x), 0x121, 0xF, 0xF, true); // ror:1
  x += __int_as_float(v);
  return x;
}

// One 8-i round. Wb: LDS chunk layout [d][jl][lane], lane bits =
// (i_sub b0-2, oq_lo b3, jg b4, oq_hi b5). Thread's j set {jl+5*jg}.
template <int PASS, int R, bool PART>
__device__ __forceinline__ void compute_round(
    const float* __restrict__ x, const float* __restrict__ v0p,
    const float* __restrict__ v1p, float* __restrict__ outp, const float* Wb,
    int i, int b0, int lane, int vbase, size_t obase) {
  constexpr size_t BBS = PART ? (size_t)(NCHUNK * SLOTS) : (size_t)SLOTS;
  const float* wsl = Wb + lane * 4;

  // load + f16-pack x rows for the wave's two batch elements (8 regs)
  h2 xh[2][4];
#pragma unroll
  for (int bb = 0; bb < 2; ++bb) {
    const float* px = x + ((size_t)(b0 + bb) * NUM_IN + i) * 8;
    const float4 a = *reinterpret_cast<const float4*>(px);
    const float4 c = *reinterpret_cast<const float4*>(px + 4);
    xh[bb][0] = __builtin_amdgcn_cvt_pkrtz(a.x, a.y);
    xh[bb][1] = __builtin_amdgcn_cvt_pkrtz(a.z, a.w);
    xh[bb][2] = __builtin_amdgcn_cvt_pkrtz(c.x, c.y);
    xh[bb][3] = __builtin_amdgcn_cvt_pkrtz(c.z, c.w);
  }

  float cw[2][5];   // logits, then coupling coefficients
  h2 up[2][5][2];   // f16-packed u-cache (20 regs)

  if (PASS >= 1) {
    // ---- phase A: u_hat (f32) -> pack; logits from f32 u ----
#pragma unroll
    for (int jl = 0; jl < 5; ++jl) {
      float ax0 = 0.f, ay0 = 0.f, az0 = 0.f, aw0 = 0.f;
      float ax1 = 0.f, ay1 = 0.f, az1 = 0.f, aw1 = 0.f;
#pragma unroll
      for (int d = 0; d < 8; ++d) {
        const float4 w =
            *reinterpret_cast<const float4*>(wsl + (d * 5 + jl) * 256);
        const float x0 = (float)xh[0][d >> 1][d & 1];
        const float x1 = (float)xh[1][d >> 1][d & 1];
        ax0 = fmaf(x0, w.x, ax0); ay0 = fmaf(x0, w.y, ay0);
        az0 = fmaf(x0, w.z, az0); aw0 = fmaf(x0, w.w, aw0);
        ax1 = fmaf(x1, w.x, ax1); ay1 = fmaf(x1, w.y, ay1);
        az1 = fmaf(x1, w.z, az1); aw1 = fmaf(x1, w.w, aw1);
      }
      up[0][jl][0] = __builtin_amdgcn_cvt_pkrtz(ax0, ay0);
      up[0][jl][1] = __builtin_amdgcn_cvt_pkrtz(az0, aw0);
      up[1][jl][0] = __builtin_amdgcn_cvt_pkrtz(ax1, ay1);
      up[1][jl][1] = __builtin_amdgcn_cvt_pkrtz(az1, aw1);

      const float4 p0 = *reinterpret_cast<const float4*>(
          v0p + (b0 + 0) * SLOTS + vbase + jl * 16);
      const float4 p1 = *reinterpret_cast<const float4*>(
          v0p + (b0 + 1) * SLOTS + vbase + jl * 16);
      float l0 = ax0 * p0.x + ay0 * p0.y + az0 * p0.z + aw0 * p0.w;
      float l1 = ax1 * p1.x + ay1 * p1.y + az1 * p1.z + aw1 * p1.w;
      if (PASS == 2) {
        const float4 q0 = *reinterpret_cast<const float4*>(
            v1p + (b0 + 0) * SLOTS + vbase + jl * 16);
        const float4 q1 = *reinterpret_cast<const float4*>(
            v1p + (b0 + 1) * SLOTS + vbase + jl * 16);
        l0 += ax0 * q0.x + ay0 * q0.y + az0 * q0.z + aw0 * q0.w;
        l1 += ax1 * q1.x + ay1 * q1.y + az1 * q1.z + aw1 * q1.w;
      }
      // o-reduce over lane bits 3 (DPP) and 5 (permlane): all-VALU.
      cw[0][jl] = xor32_sum(xor8_sum(l0));
      cw[1][jl] = xor32_sum(xor8_sum(l1));
    }
    // softmax over 10 j (partner 5 j's in the jg-partner lane, bit 4)
#pragma unroll
    for (int bb = 0; bb < 2; ++bb) {
      float m = cw[bb][0];
#pragma unroll
      for (int jl = 1; jl < 5; ++jl) m = fmaxf(m, cw[bb][jl]);
      m = fmaxf(m, __shfl_xor(m, 16));
      float z = 0.f;
#pragma unroll
      for (int jl = 0; jl < 5; ++jl) {
        cw[bb][jl] = __expf(cw[bb][jl] - m);
        z += cw[bb][jl];
      }
      z += __shfl_xor(z, 16);
      const float rz = 1.0f / z;
#pragma unroll
      for (int jl = 0; jl < 5; ++jl) cw[bb][jl] *= rz;
    }
  }

  // ---- phase C: weight u, reduce over 8 i_sub lanes, store ----
  const bool wr = ((lane & 7) == 7);
#pragma unroll
  for (int jl = 0; jl < 5; ++jl) {
    float u0[4], u1[4];
    if (PASS == 0) {
      // single-phase: compute u directly (c is uniform 0.1)
      float ax0 = 0.f, ay0 = 0.f, az0 = 0.f, aw0 = 0.f;
      float ax1 = 0.f, ay1 = 0.f, az1 = 0.f, aw1 = 0.f;
#pragma unroll
      for (int d = 0; d < 8; ++d) {
        const float4 w =
            *reinterpret_cast<const float4*>(wsl + (d * 5 + jl) * 256);
        const float x0 = (float)xh[0][d >> 1][d & 1];
        const float x1 = (float)xh[1][d >> 1][d & 1];
        ax0 = fmaf(x0, w.x, ax0); ay0 = fmaf(x0, w.y, ay0);
        az0 = fmaf(x0, w.z, az0); aw0 = fmaf(x0, w.w, aw0);
        ax1 = fmaf(x1, w.x, ax1); ay1 = fmaf(x1, w.y, ay1);
        az1 = fmaf(x1, w.z, az1); aw1 = fmaf(x1, w.w, aw1);
      }
      u0[0] = ax0 * 0.1f; u0[1] = ay0 * 0.1f;
      u0[2] = az0 * 0.1f; u0[3] = aw0 * 0.1f;
      u1[0] = ax1 * 0.1f; u1[1] = ay1 * 0.1f;
      u1[2] = az1 * 0.1f; u1[3] = aw1 * 0.1f;
    } else {
      u0[0] = cw[0][jl] * (float)up[0][jl][0].x;
      u0[1] = cw[0][jl] * (float)up[0][jl][0].y;
      u0[2] = cw[0][jl] * (float)up[0][jl][1].x;
      u0[3] = cw[0][jl] * (float)up[0][jl][1].y;
      u1[0] = cw[1][jl] * (float)up[1][jl][0].x;
      u1[1] = cw[1][jl] * (float)up[1][jl][0].y;
      u1[2] = cw[1][jl] * (float)up[1][jl][1].x;
      u1[3] = cw[1][jl] * (float)up[1][jl][1].y;
    }
    const float sx0 = rowsum8_hi(u0[0]);
    const float sy0 = rowsum8_hi(u0[1]);
    const float sz0 = rowsum8_hi(u0[2]);
    const float sw0 = rowsum8_hi(u0[3]);
    const float sx1 = rowsum8_hi(u1[0]);
    const float sy1 = rowsum8_hi(u1[1]);
    const float sz1 = rowsum8_hi(u1[2]);
    const float sw1 = rowsum8_hi(u1[3]);
    if (wr) {
      if (PART) {
        float4* q0 = reinterpret_cast<float4*>(outp + obase + 0 * BBS + jl * 16);
        float4* q1 = reinterpret_cast<float4*>(outp + obase + 1 * BBS + jl * 16);
        float4 f0 = {sx0, sy0, sz0, sw0};
        float4 f1 = {sx1, sy1, sz1, sw1};
        if (R == 1) {
          const float4 o0 = *q0, o1 = *q1;
          f0.x += o0.x; f0.y += o0.y; f0.z += o0.z; f0.w += o0.w;
          f1.x += o1.x; f1.y += o1.y; f1.z += o1.z; f1.w += o1.w;
        }
        *q0 = f0;
        *q1 = f1;
      } else {
        float* p0 = outp + obase + 0 * BBS + jl * 16;
        float* p1 = outp + obase + 1 * BBS + jl * 16;
        atomicAdd(p0 + 0, sx0); atomicAdd(p0 + 1, sy0);
        atomicAdd(p0 + 2, sz0); atomicAdd(p0 + 3, sw0);
        atomicAdd(p1 + 0, sx1); atomicAdd(p1 + 1, sy1);
        atomicAdd(p1 + 2, sz1); atomicAdd(p1 + 3, sw1);
      }
    }
  }
}

template <int PASS, bool PART>
__global__ __launch_bounds__(512, 4) void caps_pass(
    const float* __restrict__ x, const float* __restrict__ W,
    const float* __restrict__ v0, const float* __restrict__ v1,
    float* __restrict__ outp) {
  __shared__ float Ws[10240];  // single 40KB buffer -> 4 blocks/CU

  const int t = threadIdx.x;
  const int ic = blockIdx.x % NCHUNK;
  const int bt = blockIdx.x / NCHUNK;
  const int i0 = ic * ICH_BLK;

  const int lane = t & 63;
  const int wave = t >> 6;
  const int i_sub = lane & 7;                            // DPP 8-group axis
  const int oq = ((lane >> 3) & 1) | ((lane >> 4) & 2);  // bits 3,5
  const int jg = (lane >> 4) & 1;                        // bit 4
  const int b0 = bt * BPB + wave * 2;
  const int vbase = jg * 80 + oq * 4;
  const size_t obase = PART ? ((size_t)b0 * NCHUNK + ic) * SLOTS + vbase
                            : (size_t)b0 * SLOTS + vbase;

  const float* wg = W + (size_t)i0 * WROW;

  // ---- stage round 0 (per-lane global source, linear LDS dest) ----
#pragma unroll
  for (int k = 0; k < 5; ++k) {
    const int p = t + k * 512;
    const int lp = p & 63;
    const int dj = p >> 6;
    const int d = dj / 5, jl = dj - d * 5;
    const int g = (lp & 7) * 320 + d * 40 + jl * 4 + ((lp >> 4) & 1) * 20 +
                  ((lp >> 3) & 1) + ((lp >> 5) & 1) * 2;
    gll16(wg + g * 4, &Ws[p * 4]);
  }
  asm volatile("s_waitcnt vmcnt(0)" ::: "memory");
  __builtin_amdgcn_s_barrier();

  compute_round<PASS, 0, PART>(x, v0, v1, outp, Ws, i0 + i_sub, b0, lane,
                               vbase, obase);

  asm volatile("s_waitcnt lgkmcnt(0)" ::: "memory");  // all reads of Ws done
  __builtin_amdgcn_s_barrier();

  // ---- stage round 1 into the same buffer ----
#pragma unroll
  for (int k = 0; k < 5; ++k) {
    const int p = t + k * 512;
    const int lp = p & 63;
    const int dj = p >> 6;
    const int d = dj / 5, jl = dj - d * 5;
    const int g = (lp & 7) * 320 + d * 40 + jl * 4 + ((lp >> 4) & 1) * 20 +
                  ((lp >> 3) & 1) + ((lp >> 5) & 1) * 2;
    gll16(wg + 8 * WROW + g * 4, &Ws[p * 4]);
  }
  asm volatile("s_waitcnt vmcnt(0)" ::: "memory");
  __builtin_amdgcn_s_barrier();

  compute_round<PASS, 1, PART>(x, v0, v1, outp, Ws, i0 + 8 + i_sub, b0, lane,
                               vbase, obase);
}

// v = squash(sum_ic part[b][ic][:]). One block per batch element; part in
// [b][ic][slot] layout -> 640B-stride coalesced reads.
__global__ __launch_bounds__(192) void caps_reduce_squash(
    const float* __restrict__ part, float* __restrict__ v_out) {
  const int b = blockIdx.x;
  const int t = threadIdx.x;
  if (t < SLOTS) {
    const float* pb = part + (size_t)b * NCHUNK * SLOTS + t;
    float sv = 0.0f;
#pragma unroll 8
    for (int ic = 0; ic < NCHUNK; ++ic) sv += pb[ic * SLOTS];
    const float sq = rowsum16(sv * sv);  // 16-lane rows == one j each
    const float scale = sq / (1.0f + sq) * rsqrtf(sq + 1e-8f);
    v_out[(size_t)b * SLOTS + t] = sv * scale;
  }
}

// Fallback squash for the atomic path (s_in/s_zero alias intentionally).
__global__ __launch_bounds__(192) void caps_squash(const float* s_in,
                                                   float* v_out,
                                                   float* s_zero) {
  const int b = blockIdx.x;
  const int t = threadIdx.x;
  if (t < SLOTS) {
    const float sv = s_in[(size_t)b * SLOTS + t];
    const float sq = rowsum16(sv * sv);
    const float scale = sq / (1.0f + sq) * rsqrtf(sq + 1e-8f);
    v_out[(size_t)b * SLOTS + t] = sv * scale;
    if (s_zero) s_zero[(size_t)b * SLOTS + t] = 0.0f;
  }
}

extern "C" void kernel_launch(void* const* d_in, const int* in_sizes, int n_in,
                              void* d_out, int out_size, void* d_ws,
                              size_t ws_size, hipStream_t stream) {
  const float* x = (const float*)d_in[0];  // (256,1152,8)
  const float* W = (const float*)d_in[1];  // (1152,8,10,16)
  float* out = (float*)d_out;              // (256,10,16)

  const size_t part_elems = (size_t)NCHUNK * BATCH * SLOTS;  // 2.95M
  const size_t need = (part_elems + 2 * BATCH * SLOTS) * sizeof(float);
  const dim3 pg(NCHUNK * NBT);  // 1152 blocks

  if (ws_size >= need) {
    float* part = (float*)d_ws;      // 11.25 MiB, layout [b][ic][slot]
    float* v0 = part + part_elems;   // 160 KB
    float* v1 = v0 + BATCH * SLOTS;  // 160 KB
    caps_pass<0, true><<<pg, 512, 0, stream>>>(x, W, nullptr, nullptr, part);
    caps_reduce_squash<<<BATCH, 192, 0, stream>>>(part, v0);
    caps_pass<1, true><<<pg, 512, 0, stream>>>(x, W, v0, nullptr, part);
    caps_reduce_squash<<<BATCH, 192, 0, stream>>>(part, v1);
    caps_pass<2, true><<<pg, 512, 0, stream>>>(x, W, v0, v1, part);
    caps_reduce_squash<<<BATCH, 192, 0, stream>>>(part, out);
  } else {
    // Atomic fallback (ws only needs s + v0 + v1).
    float* s_buf = (float*)d_ws;
    float* v0 = s_buf + BATCH * SLOTS;
    float* v1 = v0 + BATCH * SLOTS;
    hipMemsetAsync(s_buf, 0, (size_t)BATCH * SLOTS * sizeof(float), stream);
    caps_pass<0, false><<<pg, 512, 0, stream>>>(x, W, nullptr, nullptr, s_buf);
    caps_squash<<<BATCH, 192, 0, stream>>>(s_buf, v0, s_buf);
    caps_pass<1, false><<<pg, 512, 0, stream>>>(x, W, v0, nullptr, s_buf);
    caps_squash<<<BATCH, 192, 0, stream>>>(s_buf, v1, s_buf);
    caps_pass<2, false><<<pg, 512, 0, stream>>>(x, W, v0, v1, s_buf);
    caps_squash<<<BATCH, 192, 0, stream>>>(s_buf, out, nullptr);
  }
}

// Round 9
// 195.214 us; speedup vs baseline: 1.6576x; 1.0101x over previous
//
#include <hip/hip_runtime.h>

// Capsule dynamic routing, MI355X (gfx950).
// x (256,1152,8) f32, W (1152,8,10,16) f32, out v (256,10,16) f32.
// R8 -> R9: R8 showed VALU instruction count is the binding constraint
// (VALUBusy 46%, occupancy 2x gave only -13%). This round halves the FMA
// stream with v_pk_fma_f32 (VOP3P packed f32, full precision):
//  - x kept as f32 d-pairs; op_sel broadcast (lo/hi) feeds the scalar x
//    into both packed lanes -> no splat movs, no f16 converts (the 80
//    cvt/round that R8 paid are gone).
//  - phase A: 320 v_fma -> 160 v_pk_fma per round.
//  - __launch_bounds__(512,3): VGPR cap ~84 for the ~75-reg live set
//    (this compiler's arg2 == blocks/CU; proven R4/R8). 3 blocks/CU.
//  - staging (global_load_lds, conflict-free chunk layout), lane map,
//    barrier structure, part [b][ic][slot], squash: unchanged from R8.

#define NUM_IN 1152
#define NUM_OUT 10
#define OUT_DIM 16
#define BATCH 256
#define SLOTS 160
#define ICH_BLK 16
#define NCHUNK (NUM_IN / ICH_BLK)  // 72
#define BPB 16                     // batch elems per block (8 waves x 2)
#define NBT (BATCH / BPB)          // 16
#define WROW 1280                  // floats per i-row of W

typedef unsigned int __attribute__((address_space(1))) as1_uint;
typedef unsigned int __attribute__((address_space(3))) as3_uint;
typedef int v2i __attribute__((ext_vector_type(2)));
typedef __fp16 h2 __attribute__((ext_vector_type(2)));
typedef float f2 __attribute__((ext_vector_type(2)));

// acc.lo += w.lo * xp.lo ; acc.hi += w.hi * xp.lo   (broadcast xp.lo)
#define PK_FMA_LO(acc, w, xp)                                         \
  asm("v_pk_fma_f32 %0, %1, %2, %0 op_sel:[0,0,0] op_sel_hi:[1,0,1]" \
      : "+v"(acc)                                                     \
      : "v"(w), "v"(xp))
// acc.lo += w.lo * xp.hi ; acc.hi += w.hi * xp.hi   (broadcast xp.hi)
#define PK_FMA_HI(acc, w, xp)                                         \
  asm("v_pk_fma_f32 %0, %1, %2, %0 op_sel:[0,1,0] op_sel_hi:[1,1,1]" \
      : "+v"(acc)                                                     \
      : "v"(w), "v"(xp))

__device__ __forceinline__ void gll16(const float* g, float* l) {
  __builtin_amdgcn_global_load_lds((const as1_uint*)g, (as3_uint*)l, 16, 0, 0);
}

// x + x^8 within each 16-lane row (row_ror:8 == xor-8 in a 16-ring).
__device__ __forceinline__ float xor8_sum(float x) {
  int v = __builtin_amdgcn_update_dpp(0, __float_as_int(x), 0x128, 0xF, 0xF, true);
  return x + __int_as_float(v);
}

// Pair-sum across the lane<32 / lane>=32 halves via permlane32_swap.
__device__ __forceinline__ float xor32_sum(float x) {
  v2i r = __builtin_amdgcn_permlane32_swap(__float_as_int(x),
                                           __float_as_int(x), false, false);
  return __int_as_float(r.x) + __int_as_float(r.y);
}

// Sum over each aligned 8-lane group via DPP row_shr; result valid at lanes
// with (lane&7)==7.
__device__ __forceinline__ float rowsum8_hi(float x) {
  int v;
  v = __builtin_amdgcn_update_dpp(0, __float_as_int(x), 0x114, 0xF, 0xF, true); // row_shr:4
  x += __int_as_float(v);
  v = __builtin_amdgcn_update_dpp(0, __float_as_int(x), 0x112, 0xF, 0xF, true); // row_shr:2
  x += __int_as_float(v);
  v = __builtin_amdgcn_update_dpp(0, __float_as_int(x), 0x111, 0xF, 0xF, true); // row_shr:1
  x += __int_as_float(v);
  return x;
}

// 16-lane full-row sum (all lanes get result) -- squash kernels.
__device__ __forceinline__ float rowsum16(float x) {
  int v;
  v = __builtin_amdgcn_update_dpp(0, __float_as_int(x), 0x128, 0xF, 0xF, true); // ror:8
  x += __int_as_float(v);
  v = __builtin_amdgcn_update_dpp(0, __float_as_int(x), 0x124, 0xF, 0xF, true); // ror:4
  x += __int_as_float(v);
  v = __builtin_amdgcn_update_dpp(0, __float_as_int(x), 0x122, 0xF, 0xF, true); // ror:2
  x += __int_as_float(v);
  v = __builtin_amdgcn_update_dpp(0, __float_as_int(x), 0x121, 0xF, 0xF, true); // ror:1
  x += __int_as_float(v);
  return x;
}

// One 8-i round. Wb: LDS chunk layout [d][jl][lane], lane bits =
// (i_sub b0-2, oq_lo b3, jg b4, oq_hi b5). Thread's j set {jl+5*jg}.
template <int PASS, int R, bool PART>
__device__ __forceinline__ void compute_round(
    const float* __restrict__ x, const float* __restrict__ v0p,
    const float* __restrict__ v1p, float* __restrict__ outp, const float* Wb,
    int i, int b0, int lane, int vbase, size_t obase) {
  constexpr size_t BBS = PART ? (size_t)(NCHUNK * SLOTS) : (size_t)SLOTS;
  const float* wsl = Wb + lane * 4;

  // x rows as f32 d-pairs: xp[bb][dp] = {x[2dp], x[2dp+1]}  (16 VGPR)
  f2 xp[2][4];
#pragma unroll
  for (int bb = 0; bb < 2; ++bb) {
    const float* px = x + ((size_t)(b0 + bb) * NUM_IN + i) * 8;
    const float4 a = *reinterpret_cast<const float4*>(px);
    const float4 c = *reinterpret_cast<const float4*>(px + 4);
    xp[bb][0] = f2{a.x, a.y};
    xp[bb][1] = f2{a.z, a.w};
    xp[bb][2] = f2{c.x, c.y};
    xp[bb][3] = f2{c.z, c.w};
  }

  float cw[2][5];  // logits, then coupling coefficients
  h2 up[2][5][2];  // f16-packed u-cache (20 regs)

  if (PASS >= 1) {
    // ---- phase A: u_hat (packed f32) -> pack to f16; logits from f32 ----
#pragma unroll
    for (int jl = 0; jl < 5; ++jl) {
      f2 a0_01 = {0.f, 0.f}, a0_23 = {0.f, 0.f};
      f2 a1_01 = {0.f, 0.f}, a1_23 = {0.f, 0.f};
#pragma unroll
      for (int dp = 0; dp < 4; ++dp) {
        const float4 wA =
            *reinterpret_cast<const float4*>(wsl + ((2 * dp) * 5 + jl) * 256);
        const float4 wB = *reinterpret_cast<const float4*>(
            wsl + ((2 * dp + 1) * 5 + jl) * 256);
        const f2 wA01 = f2{wA.x, wA.y}, wA23 = f2{wA.z, wA.w};
        const f2 wB01 = f2{wB.x, wB.y}, wB23 = f2{wB.z, wB.w};
        PK_FMA_LO(a0_01, wA01, xp[0][dp]);
        PK_FMA_LO(a0_23, wA23, xp[0][dp]);
        PK_FMA_HI(a0_01, wB01, xp[0][dp]);
        PK_FMA_HI(a0_23, wB23, xp[0][dp]);
        PK_FMA_LO(a1_01, wA01, xp[1][dp]);
        PK_FMA_LO(a1_23, wA23, xp[1][dp]);
        PK_FMA_HI(a1_01, wB01, xp[1][dp]);
        PK_FMA_HI(a1_23, wB23, xp[1][dp]);
      }
      up[0][jl][0] = __builtin_amdgcn_cvt_pkrtz(a0_01.x, a0_01.y);
      up[0][jl][1] = __builtin_amdgcn_cvt_pkrtz(a0_23.x, a0_23.y);
      up[1][jl][0] = __builtin_amdgcn_cvt_pkrtz(a1_01.x, a1_01.y);
      up[1][jl][1] = __builtin_amdgcn_cvt_pkrtz(a1_23.x, a1_23.y);

      const float4 p0 = *reinterpret_cast<const float4*>(
          v0p + (b0 + 0) * SLOTS + vbase + jl * 16);
      const float4 p1 = *reinterpret_cast<const float4*>(
          v0p + (b0 + 1) * SLOTS + vbase + jl * 16);
      f2 t0 = a0_01 * f2{p0.x, p0.y} + a0_23 * f2{p0.z, p0.w};
      f2 t1 = a1_01 * f2{p1.x, p1.y} + a1_23 * f2{p1.z, p1.w};
      if (PASS == 2) {
        const float4 q0 = *reinterpret_cast<const float4*>(
            v1p + (b0 + 0) * SLOTS + vbase + jl * 16);
        const float4 q1 = *reinterpret_cast<const float4*>(
            v1p + (b0 + 1) * SLOTS + vbase + jl * 16);
        t0 += a0_01 * f2{q0.x, q0.y} + a0_23 * f2{q0.z, q0.w};
        t1 += a1_01 * f2{q1.x, q1.y} + a1_23 * f2{q1.z, q1.w};
      }
      // o-reduce over lane bits 3 (DPP) and 5 (permlane): all-VALU.
      cw[0][jl] = xor32_sum(xor8_sum(t0.x + t0.y));
      cw[1][jl] = xor32_sum(xor8_sum(t1.x + t1.y));
    }
    // softmax over 10 j (partner 5 j's in the jg-partner lane, bit 4)
#pragma unroll
    for (int bb = 0; bb < 2; ++bb) {
      float m = cw[bb][0];
#pragma unroll
      for (int jl = 1; jl < 5; ++jl) m = fmaxf(m, cw[bb][jl]);
      m = fmaxf(m, __shfl_xor(m, 16));
      float z = 0.f;
#pragma unroll
      for (int jl = 0; jl < 5; ++jl) {
        cw[bb][jl] = __expf(cw[bb][jl] - m);
        z += cw[bb][jl];
      }
      z += __shfl_xor(z, 16);
      const float rz = 1.0f / z;
#pragma unroll
      for (int jl = 0; jl < 5; ++jl) cw[bb][jl] *= rz;
    }
  }

  // ---- phase C: weight u, reduce over 8 i_sub lanes, store ----
  const bool wr = ((lane & 7) == 7);
#pragma unroll
  for (int jl = 0; jl < 5; ++jl) {
    float u0[4], u1[4];
    if (PASS == 0) {
      // single-phase: compute u directly (c uniform 0.1), packed math
      f2 a0_01 = {0.f, 0.f}, a0_23 = {0.f, 0.f};
      f2 a1_01 = {0.f, 0.f}, a1_23 = {0.f, 0.f};
#pragma unroll
      for (int dp = 0; dp < 4; ++dp) {
        const float4 wA =
            *reinterpret_cast<const float4*>(wsl + ((2 * dp) * 5 + jl) * 256);
        const float4 wB = *reinterpret_cast<const float4*>(
            wsl + ((2 * dp + 1) * 5 + jl) * 256);
        const f2 wA01 = f2{wA.x, wA.y}, wA23 = f2{wA.z, wA.w};
        const f2 wB01 = f2{wB.x, wB.y}, wB23 = f2{wB.z, wB.w};
        PK_FMA_LO(a0_01, wA01, xp[0][dp]);
        PK_FMA_LO(a0_23, wA23, xp[0][dp]);
        PK_FMA_HI(a0_01, wB01, xp[0][dp]);
        PK_FMA_HI(a0_23, wB23, xp[0][dp]);
        PK_FMA_LO(a1_01, wA01, xp[1][dp]);
        PK_FMA_LO(a1_23, wA23, xp[1][dp]);
        PK_FMA_HI(a1_01, wB01, xp[1][dp]);
        PK_FMA_HI(a1_23, wB23, xp[1][dp]);
      }
      u0[0] = a0_01.x * 0.1f; u0[1] = a0_01.y * 0.1f;
      u0[2] = a0_23.x * 0.1f; u0[3] = a0_23.y * 0.1f;
      u1[0] = a1_01.x * 0.1f; u1[1] = a1_01.y * 0.1f;
      u1[2] = a1_23.x * 0.1f; u1[3] = a1_23.y * 0.1f;
    } else {
      u0[0] = cw[0][jl] * (float)up[0][jl][0].x;
      u0[1] = cw[0][jl] * (float)up[0][jl][0].y;
      u0[2] = cw[0][jl] * (float)up[0][jl][1].x;
      u0[3] = cw[0][jl] * (float)up[0][jl][1].y;
      u1[0] = cw[1][jl] * (float)up[1][jl][0].x;
      u1[1] = cw[1][jl] * (float)up[1][jl][0].y;
      u1[2] = cw[1][jl] * (float)up[1][jl][1].x;
      u1[3] = cw[1][jl] * (float)up[1][jl][1].y;
    }
    const float sx0 = rowsum8_hi(u0[0]);
    const float sy0 = rowsum8_hi(u0[1]);
    const float sz0 = rowsum8_hi(u0[2]);
    const float sw0 = rowsum8_hi(u0[3]);
    const float sx1 = rowsum8_hi(u1[0]);
    const float sy1 = rowsum8_hi(u1[1]);
    const float sz1 = rowsum8_hi(u1[2]);
    const float sw1 = rowsum8_hi(u1[3]);
    if (wr) {
      if (PART) {
        float4* q0 = reinterpret_cast<float4*>(outp + obase + 0 * BBS + jl * 16);
        float4* q1 = reinterpret_cast<float4*>(outp + obase + 1 * BBS + jl * 16);
        float4 f0 = {sx0, sy0, sz0, sw0};
        float4 f1 = {sx1, sy1, sz1, sw1};
        if (R == 1) {
          const float4 o0 = *q0, o1 = *q1;
          f0.x += o0.x; f0.y += o0.y; f0.z += o0.z; f0.w += o0.w;
          f1.x += o1.x; f1.y += o1.y; f1.z += o1.z; f1.w += o1.w;
        }
        *q0 = f0;
        *q1 = f1;
      } else {
        float* p0 = outp + obase + 0 * BBS + jl * 16;
        float* p1 = outp + obase + 1 * BBS + jl * 16;
        atomicAdd(p0 + 0, sx0); atomicAdd(p0 + 1, sy0);
        atomicAdd(p0 + 2, sz0); atomicAdd(p0 + 3, sw0);
        atomicAdd(p1 + 0, sx1); atomicAdd(p1 + 1, sy1);
        atomicAdd(p1 + 2, sz1); atomicAdd(p1 + 3, sw1);
      }
    }
  }
}

template <int PASS, bool PART>
__global__ __launch_bounds__(512, 3) void caps_pass(
    const float* __restrict__ x, const float* __restrict__ W,
    const float* __restrict__ v0, const float* __restrict__ v1,
    float* __restrict__ outp) {
  __shared__ float Ws[10240];  // single 40KB buffer

  const int t = threadIdx.x;
  const int ic = blockIdx.x % NCHUNK;
  const int bt = blockIdx.x / NCHUNK;
  const int i0 = ic * ICH_BLK;

  const int lane = t & 63;
  const int wave = t >> 6;
  const int i_sub = lane & 7;                            // DPP 8-group axis
  const int oq = ((lane >> 3) & 1) | ((lane >> 4) & 2);  // bits 3,5
  const int jg = (lane >> 4) & 1;                        // bit 4
  const int b0 = bt * BPB + wave * 2;
  const int vbase = jg * 80 + oq * 4;
  const size_t obase = PART ? ((size_t)b0 * NCHUNK + ic) * SLOTS + vbase
                            : (size_t)b0 * SLOTS + vbase;

  const float* wg = W + (size_t)i0 * WROW;

  // ---- stage round 0 (per-lane global source, linear LDS dest) ----
#pragma unroll
  for (int k = 0; k < 5; ++k) {
    const int p = t + k * 512;
    const int lp = p & 63;
    const int dj = p >> 6;
    const int d = dj / 5, jl = dj - d * 5;
    const int g = (lp & 7) * 320 + d * 40 + jl * 4 + ((lp >> 4) & 1) * 20 +
                  ((lp >> 3) & 1) + ((lp >> 5) & 1) * 2;
    gll16(wg + g * 4, &Ws[p * 4]);
  }
  asm volatile("s_waitcnt vmcnt(0)" ::: "memory");
  __builtin_amdgcn_s_barrier();

  compute_round<PASS, 0, PART>(x, v0, v1, outp, Ws, i0 + i_sub, b0, lane,
                               vbase, obase);

  asm volatile("s_waitcnt lgkmcnt(0)" ::: "memory");  // all reads of Ws done
  __builtin_amdgcn_s_barrier();

  // ---- stage round 1 into the same buffer ----
#pragma unroll
  for (int k = 0; k < 5; ++k) {
    const int p = t + k * 512;
    const int lp = p & 63;
    const int dj = p >> 6;
    const int d = dj / 5, jl = dj - d * 5;
    const int g = (lp & 7) * 320 + d * 40 + jl * 4 + ((lp >> 4) & 1) * 20 +
                  ((lp >> 3) & 1) + ((lp >> 5) & 1) * 2;
    gll16(wg + 8 * WROW + g * 4, &Ws[p * 4]);
  }
  asm volatile("s_waitcnt vmcnt(0)" ::: "memory");
  __builtin_amdgcn_s_barrier();

  compute_round<PASS, 1, PART>(x, v0, v1, outp, Ws, i0 + 8 + i_sub, b0, lane,
                               vbase, obase);
}

// v = squash(sum_ic part[b][ic][:]). One block per batch element; part in
// [b][ic][slot] layout -> 640B-stride coalesced reads.
__global__ __launch_bounds__(192) void caps_reduce_squash(
    const float* __restrict__ part, float* __restrict__ v_out) {
  const int b = blockIdx.x;
  const int t = threadIdx.x;
  if (t < SLOTS) {
    const float* pb = part + (size_t)b * NCHUNK * SLOTS + t;
    float sv = 0.0f;
#pragma unroll 8
    for (int ic = 0; ic < NCHUNK; ++ic) sv += pb[ic * SLOTS];
    const float sq = rowsum16(sv * sv);  // 16-lane rows == one j each
    const float scale = sq / (1.0f + sq) * rsqrtf(sq + 1e-8f);
    v_out[(size_t)b * SLOTS + t] = sv * scale;
  }
}

// Fallback squash for the atomic path (s_in/s_zero alias intentionally).
__global__ __launch_bounds__(192) void caps_squash(const float* s_in,
                                                   float* v_out,
                                                   float* s_zero) {
  const int b = blockIdx.x;
  const int t = threadIdx.x;
  if (t < SLOTS) {
    const float sv = s_in[(size_t)b * SLOTS + t];
    const float sq = rowsum16(sv * sv);
    const float scale = sq / (1.0f + sq) * rsqrtf(sq + 1e-8f);
    v_out[(size_t)b * SLOTS + t] = sv * scale;
    if (s_zero) s_zero[(size_t)b * SLOTS + t] = 0.0f;
  }
}

extern "C" void kernel_launch(void* const* d_in, const int* in_sizes, int n_in,
                              void* d_out, int out_size, void* d_ws,
                              size_t ws_size, hipStream_t stream) {
  const float* x = (const float*)d_in[0];  // (256,1152,8)
  const float* W = (const float*)d_in[1];  // (1152,8,10,16)
  float* out = (float*)d_out;              // (256,10,16)

  const size_t part_elems = (size_t)NCHUNK * BATCH * SLOTS;  // 2.95M
  const size_t need = (part_elems + 2 * BATCH * SLOTS) * sizeof(float);
  const dim3 pg(NCHUNK * NBT);  // 1152 blocks

  if (ws_size >= need) {
    float* part = (float*)d_ws;      // 11.25 MiB, layout [b][ic][slot]
    float* v0 = part + part_elems;   // 160 KB
    float* v1 = v0 + BATCH * SLOTS;  // 160 KB
    caps_pass<0, true><<<pg, 512, 0, stream>>>(x, W, nullptr, nullptr, part);
    caps_reduce_squash<<<BATCH, 192, 0, stream>>>(part, v0);
    caps_pass<1, true><<<pg, 512, 0, stream>>>(x, W, v0, nullptr, part);
    caps_reduce_squash<<<BATCH, 192, 0, stream>>>(part, v1);
    caps_pass<2, true><<<pg, 512, 0, stream>>>(x, W, v0, v1, part);
    caps_reduce_squash<<<BATCH, 192, 0, stream>>>(part, out);
  } else {
    // Atomic fallback (ws only needs s + v0 + v1).
    float* s_buf = (float*)d_ws;
    float* v0 = s_buf + BATCH * SLOTS;
    float* v1 = v0 + BATCH * SLOTS;
    hipMemsetAsync(s_buf, 0, (size_t)BATCH * SLOTS * sizeof(float), stream);
    caps_pass<0, false><<<pg, 512, 0, stream>>>(x, W, nullptr, nullptr, s_buf);
    caps_squash<<<BATCH, 192, 0, stream>>>(s_buf, v0, s_buf);
    caps_pass<1, false><<<pg, 512, 0, stream>>>(x, W, v0, nullptr, s_buf);
    caps_squash<<<BATCH, 192, 0, stream>>>(s_buf, v1, s_buf);
    caps_pass<2, false><<<pg, 512, 0, stream>>>(x, W, v0, v1, s_buf);
    caps_squash<<<BATCH, 192, 0, stream>>>(s_buf, out, nullptr);
  }
}

// Round 11
// 191.507 us; speedup vs baseline: 1.6897x; 1.0194x over previous
//
#include <hip/hip_runtime.h>

// Capsule dynamic routing, MI355X (gfx950).
// x (256,1152,8) f32, W (1152,8,10,16) f32, out v (256,10,16) f32.
// R10 resubmit (container infra failure; kernel never ran).
// R9 -> R10: R9 proved pk_fma cuts VALU issue (24.6 -> 20.3us) but (512,3)
// cut occupancy 30 -> 18.5% and net-regressed. This round combines:
//  - (512,4): VGPR cap 64 -> 4 blocks/CU, 32 waves/CU (R8's occupancy).
//    Live set shrunk to fit: pass0's u is ALSO f16-cached (uniform A/C
//    structure, no duplicated FMA block in phase C).
//  - restage overlap: phase C reads only registers for ALL passes now, so
//    round-1 staging issues right after phase A's lgkmcnt(0)+barrier and
//    flies under softmax+phaseC+stores (stage latency was fully exposed).
//  - keep: pk_fma op_sel broadcast, conflict-free chunk layout, part
//    [b][ic][slot], squash kernels.
// Spill tripwire: WRITE_SIZE must stay ~11.5MB (scratch shows up there).

#define NUM_IN 1152
#define NUM_OUT 10
#define OUT_DIM 16
#define BATCH 256
#define SLOTS 160
#define ICH_BLK 16
#define NCHUNK (NUM_IN / ICH_BLK)  // 72
#define BPB 16                     // batch elems per block (8 waves x 2)
#define NBT (BATCH / BPB)          // 16
#define WROW 1280                  // floats per i-row of W

typedef unsigned int __attribute__((address_space(1))) as1_uint;
typedef unsigned int __attribute__((address_space(3))) as3_uint;
typedef int v2i __attribute__((ext_vector_type(2)));
typedef __fp16 h2 __attribute__((ext_vector_type(2)));
typedef float f2 __attribute__((ext_vector_type(2)));

// acc.lo += w.lo * xp.lo ; acc.hi += w.hi * xp.lo   (broadcast xp.lo)
#define PK_FMA_LO(acc, w, xp)                                        \
  asm("v_pk_fma_f32 %0, %1, %2, %0 op_sel:[0,0,0] op_sel_hi:[1,0,1]" \
      : "+v"(acc)                                                    \
      : "v"(w), "v"(xp))
// acc.lo += w.lo * xp.hi ; acc.hi += w.hi * xp.hi   (broadcast xp.hi)
#define PK_FMA_HI(acc, w, xp)                                        \
  asm("v_pk_fma_f32 %0, %1, %2, %0 op_sel:[0,1,0] op_sel_hi:[1,1,1]" \
      : "+v"(acc)                                                    \
      : "v"(w), "v"(xp))

__device__ __forceinline__ void gll16(const float* g, float* l) {
  __builtin_amdgcn_global_load_lds((const as1_uint*)g, (as3_uint*)l, 16, 0, 0);
}

// x + x^8 within each 16-lane row (row_ror:8 == xor-8 in a 16-ring).
__device__ __forceinline__ float xor8_sum(float x) {
  int v = __builtin_amdgcn_update_dpp(0, __float_as_int(x), 0x128, 0xF, 0xF, true);
  return x + __int_as_float(v);
}

// Pair-sum across the lane<32 / lane>=32 halves via permlane32_swap.
__device__ __forceinline__ float xor32_sum(float x) {
  v2i r = __builtin_amdgcn_permlane32_swap(__float_as_int(x),
                                           __float_as_int(x), false, false);
  return __int_as_float(r.x) + __int_as_float(r.y);
}

// Sum over each aligned 8-lane group via DPP row_shr; result valid at lanes
// with (lane&7)==7.
__device__ __forceinline__ float rowsum8_hi(float x) {
  int v;
  v = __builtin_amdgcn_update_dpp(0, __float_as_int(x), 0x114, 0xF, 0xF, true); // row_shr:4
  x += __int_as_float(v);
  v = __builtin_amdgcn_update_dpp(0, __float_as_int(x), 0x112, 0xF, 0xF, true); // row_shr:2
  x += __int_as_float(v);
  v = __builtin_amdgcn_update_dpp(0, __float_as_int(x), 0x111, 0xF, 0xF, true); // row_shr:1
  x += __int_as_float(v);
  return x;
}

// 16-lane full-row sum (all lanes get result) -- squash kernels.
__device__ __forceinline__ float rowsum16(float x) {
  int v;
  v = __builtin_amdgcn_update_dpp(0, __float_as_int(x), 0x128, 0xF, 0xF, true); // ror:8
  x += __int_as_float(v);
  v = __builtin_amdgcn_update_dpp(0, __float_as_int(x), 0x124, 0xF, 0xF, true); // ror:4
  x += __int_as_float(v);
  v = __builtin_amdgcn_update_dpp(0, __float_as_int(x), 0x122, 0xF, 0xF, true); // ror:2
  x += __int_as_float(v);
  v = __builtin_amdgcn_update_dpp(0, __float_as_int(x), 0x121, 0xF, 0xF, true); // ror:1
  x += __int_as_float(v);
  return x;
}

// Phase A for one 8-i round: compute u_hat (packed f32), cache as f16 in
// up[][][]; for PASS>=1 also logits + softmax into cw (PASS0: cw = 0.1).
// Wb chunk layout [d][jl][lane]; lane bits (i_sub b0-2, oq_lo b3, jg b4,
// oq_hi b5); this thread's j set {jl + 5*jg}. Reads Ws; nothing after this
// function touches LDS (phase C is register-only).
template <int PASS>
__device__ __forceinline__ void phase_A(const float* __restrict__ x,
                                        const float* __restrict__ v0p,
                                        const float* __restrict__ v1p,
                                        const float* Wb, int i, int b0,
                                        int lane, int vbase, float cw[2][5],
                                        h2 up[2][5][2]) {
  const float* wsl = Wb + lane * 4;

  // x rows as f32 d-pairs: xp[bb][dp] = {x[2dp], x[2dp+1]}
  f2 xp[2][4];
#pragma unroll
  for (int bb = 0; bb < 2; ++bb) {
    const float* px = x + ((size_t)(b0 + bb) * NUM_IN + i) * 8;
    const float4 a = *reinterpret_cast<const float4*>(px);
    const float4 c = *reinterpret_cast<const float4*>(px + 4);
    xp[bb][0] = f2{a.x, a.y};
    xp[bb][1] = f2{a.z, a.w};
    xp[bb][2] = f2{c.x, c.y};
    xp[bb][3] = f2{c.z, c.w};
  }

#pragma unroll
  for (int jl = 0; jl < 5; ++jl) {
    f2 a0_01 = {0.f, 0.f}, a0_23 = {0.f, 0.f};
    f2 a1_01 = {0.f, 0.f}, a1_23 = {0.f, 0.f};
#pragma unroll
    for (int dp = 0; dp < 4; ++dp) {
      const float4 wA =
          *reinterpret_cast<const float4*>(wsl + ((2 * dp) * 5 + jl) * 256);
      const float4 wB = *reinterpret_cast<const float4*>(
          wsl + ((2 * dp + 1) * 5 + jl) * 256);
      const f2 wA01 = f2{wA.x, wA.y}, wA23 = f2{wA.z, wA.w};
      const f2 wB01 = f2{wB.x, wB.y}, wB23 = f2{wB.z, wB.w};
      PK_FMA_LO(a0_01, wA01, xp[0][dp]);
      PK_FMA_LO(a0_23, wA23, xp[0][dp]);
      PK_FMA_HI(a0_01, wB01, xp[0][dp]);
      PK_FMA_HI(a0_23, wB23, xp[0][dp]);
      PK_FMA_LO(a1_01, wA01, xp[1][dp]);
      PK_FMA_LO(a1_23, wA23, xp[1][dp]);
      PK_FMA_HI(a1_01, wB01, xp[1][dp]);
      PK_FMA_HI(a1_23, wB23, xp[1][dp]);
    }
    up[0][jl][0] = __builtin_amdgcn_cvt_pkrtz(a0_01.x, a0_01.y);
    up[0][jl][1] = __builtin_amdgcn_cvt_pkrtz(a0_23.x, a0_23.y);
    up[1][jl][0] = __builtin_amdgcn_cvt_pkrtz(a1_01.x, a1_01.y);
    up[1][jl][1] = __builtin_amdgcn_cvt_pkrtz(a1_23.x, a1_23.y);

    if (PASS >= 1) {
      const float4 p0 = *reinterpret_cast<const float4*>(
          v0p + (b0 + 0) * SLOTS + vbase + jl * 16);
      const float4 p1 = *reinterpret_cast<const float4*>(
          v0p + (b0 + 1) * SLOTS + vbase + jl * 16);
      f2 t0 = a0_01 * f2{p0.x, p0.y} + a0_23 * f2{p0.z, p0.w};
      f2 t1 = a1_01 * f2{p1.x, p1.y} + a1_23 * f2{p1.z, p1.w};
      if (PASS == 2) {
        const float4 q0 = *reinterpret_cast<const float4*>(
            v1p + (b0 + 0) * SLOTS + vbase + jl * 16);
        const float4 q1 = *reinterpret_cast<const float4*>(
            v1p + (b0 + 1) * SLOTS + vbase + jl * 16);
        t0 += a0_01 * f2{q0.x, q0.y} + a0_23 * f2{q0.z, q0.w};
        t1 += a1_01 * f2{q1.x, q1.y} + a1_23 * f2{q1.z, q1.w};
      }
      // o-reduce over lane bits 3 (DPP) and 5 (permlane): all-VALU.
      cw[0][jl] = xor32_sum(xor8_sum(t0.x + t0.y));
      cw[1][jl] = xor32_sum(xor8_sum(t1.x + t1.y));
    }
  }

  if (PASS == 0) {
#pragma unroll
    for (int bb = 0; bb < 2; ++bb)
#pragma unroll
      for (int jl = 0; jl < 5; ++jl) cw[bb][jl] = 0.1f;
  } else {
    // softmax over 10 j (partner 5 j's in the jg-partner lane, bit 4)
#pragma unroll
    for (int bb = 0; bb < 2; ++bb) {
      float m = cw[bb][0];
#pragma unroll
      for (int jl = 1; jl < 5; ++jl) m = fmaxf(m, cw[bb][jl]);
      m = fmaxf(m, __shfl_xor(m, 16));
      float z = 0.f;
#pragma unroll
      for (int jl = 0; jl < 5; ++jl) {
        cw[bb][jl] = __expf(cw[bb][jl] - m);
        z += cw[bb][jl];
      }
      z += __shfl_xor(z, 16);
      const float rz = 1.0f / z;
#pragma unroll
      for (int jl = 0; jl < 5; ++jl) cw[bb][jl] *= rz;
    }
  }
}

// Phase C: register-only. Weight cached u by cw, reduce over 8 i_sub lanes,
// store/accumulate the partial s.
template <int R, bool PART>
__device__ __forceinline__ void phase_C(float* __restrict__ outp,
                                        const float cw[2][5],
                                        const h2 up[2][5][2], int lane,
                                        size_t obase) {
  constexpr size_t BBS = PART ? (size_t)(NCHUNK * SLOTS) : (size_t)SLOTS;
  const bool wr = ((lane & 7) == 7);
#pragma unroll
  for (int jl = 0; jl < 5; ++jl) {
    const float sx0 = rowsum8_hi(cw[0][jl] * (float)up[0][jl][0].x);
    const float sy0 = rowsum8_hi(cw[0][jl] * (float)up[0][jl][0].y);
    const float sz0 = rowsum8_hi(cw[0][jl] * (float)up[0][jl][1].x);
    const float sw0 = rowsum8_hi(cw[0][jl] * (float)up[0][jl][1].y);
    const float sx1 = rowsum8_hi(cw[1][jl] * (float)up[1][jl][0].x);
    const float sy1 = rowsum8_hi(cw[1][jl] * (float)up[1][jl][0].y);
    const float sz1 = rowsum8_hi(cw[1][jl] * (float)up[1][jl][1].x);
    const float sw1 = rowsum8_hi(cw[1][jl] * (float)up[1][jl][1].y);
    if (wr) {
      if (PART) {
        float4* q0 =
            reinterpret_cast<float4*>(outp + obase + 0 * BBS + jl * 16);
        float4* q1 =
            reinterpret_cast<float4*>(outp + obase + 1 * BBS + jl * 16);
        float4 f0 = {sx0, sy0, sz0, sw0};
        float4 f1 = {sx1, sy1, sz1, sw1};
        if (R == 1) {
          const float4 o0 = *q0, o1 = *q1;
          f0.x += o0.x; f0.y += o0.y; f0.z += o0.z; f0.w += o0.w;
          f1.x += o1.x; f1.y += o1.y; f1.z += o1.z; f1.w += o1.w;
        }
        *q0 = f0;
        *q1 = f1;
      } else {
        float* p0 = outp + obase + 0 * BBS + jl * 16;
        float* p1 = outp + obase + 1 * BBS + jl * 16;
        atomicAdd(p0 + 0, sx0); atomicAdd(p0 + 1, sy0);
        atomicAdd(p0 + 2, sz0); atomicAdd(p0 + 3, sw0);
        atomicAdd(p1 + 0, sx1); atomicAdd(p1 + 1, sy1);
        atomicAdd(p1 + 2, sz1); atomicAdd(p1 + 3, sw1);
      }
    }
  }
}

template <int PASS, bool PART>
__global__ __launch_bounds__(512, 4) void caps_pass(
    const float* __restrict__ x, const float* __restrict__ W,
    const float* __restrict__ v0, const float* __restrict__ v1,
    float* __restrict__ outp) {
  __shared__ float Ws[10240];  // single 40KB buffer -> 4 blocks/CU

  const int t = threadIdx.x;
  const int ic = blockIdx.x % NCHUNK;
  const int bt = blockIdx.x / NCHUNK;
  const int i0 = ic * ICH_BLK;

  const int lane = t & 63;
  const int wave = t >> 6;
  const int i_sub = lane & 7;                            // DPP 8-group axis
  const int oq = ((lane >> 3) & 1) | ((lane >> 4) & 2);  // bits 3,5
  const int jg = (lane >> 4) & 1;                        // bit 4
  const int b0 = bt * BPB + wave * 2;
  const int vbase = jg * 80 + oq * 4;
  const size_t obase = PART ? ((size_t)b0 * NCHUNK + ic) * SLOTS + vbase
                            : (size_t)b0 * SLOTS + vbase;

  const float* wg = W + (size_t)i0 * WROW;

  // ---- stage round 0 (per-lane global source, linear LDS dest) ----
#pragma unroll
  for (int k = 0; k < 5; ++k) {
    const int p = t + k * 512;
    const int lp = p & 63;
    const int dj = p >> 6;
    const int d = dj / 5, jl = dj - d * 5;
    const int g = (lp & 7) * 320 + d * 40 + jl * 4 + ((lp >> 4) & 1) * 20 +
                  ((lp >> 3) & 1) + ((lp >> 5) & 1) * 2;
    gll16(wg + g * 4, &Ws[p * 4]);
  }
  asm volatile("s_waitcnt vmcnt(0)" ::: "memory");
  __builtin_amdgcn_s_barrier();

  float cw[2][5];
  h2 up[2][5][2];

  // ---- round 0, phase A (all LDS reads of Ws happen here) ----
  phase_A<PASS>(x, v0, v1, Ws, i0 + i_sub, b0, lane, vbase, cw, up);

  asm volatile("s_waitcnt lgkmcnt(0)" ::: "memory");  // Ws reads retired
  __builtin_amdgcn_s_barrier();

  // ---- stage round 1 NOW; it flies under softmax-tail + phase C ----
#pragma unroll
  for (int k = 0; k < 5; ++k) {
    const int p = t + k * 512;
    const int lp = p & 63;
    const int dj = p >> 6;
    const int d = dj / 5, jl = dj - d * 5;
    const int g = (lp & 7) * 320 + d * 40 + jl * 4 + ((lp >> 4) & 1) * 20 +
                  ((lp >> 3) & 1) + ((lp >> 5) & 1) * 2;
    gll16(wg + 8 * WROW + g * 4, &Ws[p * 4]);
  }

  // ---- round 0, phase C (register-only) ----
  phase_C<0, PART>(outp, cw, up, lane, obase);

  asm volatile("s_waitcnt vmcnt(0)" ::: "memory");  // round-1 buffer ready
  __builtin_amdgcn_s_barrier();

  // ---- round 1 ----
  phase_A<PASS>(x, v0, v1, Ws, i0 + 8 + i_sub, b0, lane, vbase, cw, up);
  phase_C<1, PART>(outp, cw, up, lane, obase);
}

// v = squash(sum_ic part[b][ic][:]). One block per batch element; part in
// [b][ic][slot] layout -> 640B-stride coalesced reads.
__global__ __launch_bounds__(192) void caps_reduce_squash(
    const float* __restrict__ part, float* __restrict__ v_out) {
  const int b = blockIdx.x;
  const int t = threadIdx.x;
  if (t < SLOTS) {
    const float* pb = part + (size_t)b * NCHUNK * SLOTS + t;
    float sv = 0.0f;
#pragma unroll 8
    for (int ic = 0; ic < NCHUNK; ++ic) sv += pb[ic * SLOTS];
    const float sq = rowsum16(sv * sv);  // 16-lane rows == one j each
    const float scale = sq / (1.0f + sq) * rsqrtf(sq + 1e-8f);
    v_out[(size_t)b * SLOTS + t] = sv * scale;
  }
}

// Fallback squash for the atomic path (s_in/s_zero alias intentionally).
__global__ __launch_bounds__(192) void caps_squash(const float* s_in,
                                                   float* v_out,
                                                   float* s_zero) {
  const int b = blockIdx.x;
  const int t = threadIdx.x;
  if (t < SLOTS) {
    const float sv = s_in[(size_t)b * SLOTS + t];
    const float sq = rowsum16(sv * sv);
    const float scale = sq / (1.0f + sq) * rsqrtf(sq + 1e-8f);
    v_out[(size_t)b * SLOTS + t] = sv * scale;
    if (s_zero) s_zero[(size_t)b * SLOTS + t] = 0.0f;
  }
}

extern "C" void kernel_launch(void* const* d_in, const int* in_sizes, int n_in,
                              void* d_out, int out_size, void* d_ws,
                              size_t ws_size, hipStream_t stream) {
  const float* x = (const float*)d_in[0];  // (256,1152,8)
  const float* W = (const float*)d_in[1];  // (1152,8,10,16)
  float* out = (float*)d_out;              // (256,10,16)

  const size_t part_elems = (size_t)NCHUNK * BATCH * SLOTS;  // 2.95M
  const size_t need = (part_elems + 2 * BATCH * SLOTS) * sizeof(float);
  const dim3 pg(NCHUNK * NBT);  // 1152 blocks

  if (ws_size >= need) {
    float* part = (float*)d_ws;      // 11.25 MiB, layout [b][ic][slot]
    float* v0 = part + part_elems;   // 160 KB
    float* v1 = v0 + BATCH * SLOTS;  // 160 KB
    caps_pass<0, true><<<pg, 512, 0, stream>>>(x, W, nullptr, nullptr, part);
    caps_reduce_squash<<<BATCH, 192, 0, stream>>>(part, v0);
    caps_pass<1, true><<<pg, 512, 0, stream>>>(x, W, v0, nullptr, part);
    caps_reduce_squash<<<BATCH, 192, 0, stream>>>(part, v1);
    caps_pass<2, true><<<pg, 512, 0, stream>>>(x, W, v0, v1, part);
    caps_reduce_squash<<<BATCH, 192, 0, stream>>>(part, out);
  } else {
    // Atomic fallback (ws only needs s + v0 + v1).
    float* s_buf = (float*)d_ws;
    float* v0 = s_buf + BATCH * SLOTS;
    float* v1 = v0 + BATCH * SLOTS;
    hipMemsetAsync(s_buf, 0, (size_t)BATCH * SLOTS * sizeof(float), stream);
    caps_pass<0, false><<<pg, 512, 0, stream>>>(x, W, nullptr, nullptr, s_buf);
    caps_squash<<<BATCH, 192, 0, stream>>>(s_buf, v0, s_buf);
    caps_pass<1, false><<<pg, 512, 0, stream>>>(x, W, v0, nullptr, s_buf);
    caps_squash<<<BATCH, 192, 0, stream>>>(s_buf, v1, s_buf);
    caps_pass<2, false><<<pg, 512, 0, stream>>>(x, W, v0, v1, s_buf);
    caps_squash<<<BATCH, 192, 0, stream>>>(s_buf, out, nullptr);
  }
}